// Round 1
// baseline (485.069 us; speedup 1.0000x reference)
//
#include <hip/hip_runtime.h>

// RelationNetwork fused pipeline for MI355X (gfx950).
// B=64, N=64, D=64, T=128, HG=256, HF=128, OUT=128. M = B*N*N = 262144 pair rows.
//
// Pipeline:
//  k_wt     : transpose+convert gW1 -> W1T (f16, [n][k]), gW2 -> W2T
//  k_prep   : U = x@W0[:64], V = x@W0[64:]  (fp32, 4096x256 each)
//  k_stats0 : per-b sums of U,V,U^2,V^2  (layer-0 BN stats in closed form)
//  k_bn0    : fold BN0 -> c0s (scale), c0t (shift incl. bias/beta)
//  k_uv     : U' = c0s*U + c0t, V' = c0s*V   (f16)
//  k_gemm1  : Z1 = relu(U'+V') @ W1 + b1  (f16 MFMA, a0 generated on the fly),
//             + per-column sum/sumsq atomics (32 replicas)
//  k_bn1    : finalize BN1 params
//  k_gemm23<0>: stats pass: z2 = relu(bn1(Z1)) @ W2 + b2 -> column sum/sumsq only
//  k_bn2    : finalize BN2 params
//  k_gemm23<1>: final pass: recompute z2, a2 = relu(bn2(z2)), reduce rows -> s[b][c]
//  k_f      : tiny F-MLP (BN over 64 rows) + final linear -> out (64x128 fp32)

typedef _Float16 half8 __attribute__((ext_vector_type(8)));
typedef _Float16 half4_t __attribute__((ext_vector_type(4)));
typedef float float4_t __attribute__((ext_vector_type(4)));

static constexpr float kEps = 1e-5f;
static constexpr float kM = 262144.f;

// ---- workspace layout (bytes) ----
static constexpr size_t OFF_U   = 0;                                  // 4096*256 f32
static constexpr size_t OFF_V   = OFF_U  + (size_t)4096*256*4;
static constexpr size_t OFF_UP  = OFF_V  + (size_t)4096*256*4;        // f16
static constexpr size_t OFF_VP  = OFF_UP + (size_t)4096*256*2;
static constexpr size_t OFF_W1T = OFF_VP + (size_t)4096*256*2;        // 256x256 f16 [n][k]
static constexpr size_t OFF_W2T = OFF_W1T + (size_t)256*256*2;        // 128x256 f16 [n][k]
static constexpr size_t OFF_Z1  = OFF_W2T + (size_t)128*256*2;        // 262144x256 f16
static constexpr size_t OFF_ST0 = OFF_Z1 + (size_t)262144*256*2;      // 64*4*256 f32
static constexpr size_t OFF_C0S = OFF_ST0 + (size_t)64*4*256*4;
static constexpr size_t OFF_C0T = OFF_C0S + 1024;
static constexpr size_t OFF_C1S = OFF_C0T + 1024;
static constexpr size_t OFF_C1T = OFF_C1S + 1024;
static constexpr size_t OFF_C2S = OFF_C1T + 1024;
static constexpr size_t OFF_C2T = OFF_C2S + 512;
static constexpr size_t OFF_ST1 = OFF_C2T + 512;                      // 32*512 f32 (zeroed)
static constexpr size_t OFF_ST2 = OFF_ST1 + (size_t)32*512*4;         // 32*256 f32 (zeroed)
static constexpr size_t OFF_SB  = OFF_ST2 + (size_t)32*256*4;         // 64*128 f32 (zeroed)
static constexpr size_t ZERO_BYTES = (size_t)32*512*4 + (size_t)32*256*4 + (size_t)64*128*4;

static __device__ inline half8 relu8(half8 s) {
#pragma unroll
  for (int e = 0; e < 8; ++e) s[e] = s[e] > (_Float16)0 ? s[e] : (_Float16)0;
  return s;
}

// ---- W transpose/convert: W1T[n*256+k] = gW1[k*256+n]; W2T[n*256+k] = gW2[k*128+n]
__global__ __launch_bounds__(256) void k_wt(const float* __restrict__ gW1,
                                            const float* __restrict__ gW2,
                                            _Float16* __restrict__ W1T,
                                            _Float16* __restrict__ W2T) {
  int idx = blockIdx.x * 256 + threadIdx.x;
  if (idx < 65536) {
    int n = idx >> 8, k = idx & 255;
    W1T[idx] = (_Float16)gW1[k * 256 + n];
  } else if (idx < 98304) {
    int j = idx - 65536;
    int n = j >> 8, k = j & 255;
    W2T[j] = (_Float16)gW2[k * 128 + n];
  }
}

// ---- U = x @ W0[0:64,:], V = x @ W0[64:128,:]   (fp32)
// grid (128, 4): bx = 32-row p-block, by: {0,1}->U cols {0..127,128..255}, {2,3}->V
__global__ __launch_bounds__(256) void k_prep(const float* __restrict__ x,
                                              const float* __restrict__ gW0,
                                              float* __restrict__ U,
                                              float* __restrict__ V) {
  __shared__ __align__(16) float sX[32 * 64];
  int t = threadIdx.x;
  int p0 = blockIdx.x * 32;
  int by = blockIdx.y;
  int hsel = by >> 1;
  int cbase = (by & 1) * 128;
#pragma unroll
  for (int it = 0; it < 2; ++it) {
    int f4 = (it * 256 + t) * 4;
    *(float4_t*)(sX + f4) = *(const float4_t*)(x + (size_t)p0 * 64 + f4);
  }
  __syncthreads();
  int r = t >> 3, cg = (t & 7) * 16;
  const float* Wb = gW0 + (size_t)(hsel * 64) * 256 + cbase + cg;
  float acc[16];
#pragma unroll
  for (int j = 0; j < 16; ++j) acc[j] = 0.f;
  for (int k = 0; k < 64; ++k) {
    float xv = sX[r * 64 + k];
    const float4_t* wr = (const float4_t*)(Wb + (size_t)k * 256);
    float4_t w0 = wr[0], w1 = wr[1], w2 = wr[2], w3 = wr[3];
#pragma unroll
    for (int j = 0; j < 4; ++j) {
      acc[j]      += xv * w0[j];
      acc[4 + j]  += xv * w1[j];
      acc[8 + j]  += xv * w2[j];
      acc[12 + j] += xv * w3[j];
    }
  }
  float* outp = (hsel ? V : U) + (size_t)(p0 + r) * 256 + cbase + cg;
#pragma unroll
  for (int q = 0; q < 4; ++q) {
    float4_t o = {acc[q * 4], acc[q * 4 + 1], acc[q * 4 + 2], acc[q * 4 + 3]};
    *(float4_t*)(outp + q * 4) = o;
  }
}

// ---- per-b sums for layer-0 closed-form BN stats
__global__ __launch_bounds__(256) void k_stats0(const float* __restrict__ U,
                                                const float* __restrict__ V,
                                                float* __restrict__ st0) {
  int b = blockIdx.x, c = threadIdx.x;
  float su = 0, su2 = 0, sv = 0, sv2 = 0;
  for (int i = 0; i < 64; ++i) {
    float u = U[(size_t)(b * 64 + i) * 256 + c];
    float v = V[(size_t)(b * 64 + i) * 256 + c];
    su += u; su2 += u * u; sv += v; sv2 += v * v;
  }
  st0[(b * 4 + 0) * 256 + c] = su;
  st0[(b * 4 + 1) * 256 + c] = su2;
  st0[(b * 4 + 2) * 256 + c] = sv;
  st0[(b * 4 + 3) * 256 + c] = sv2;
}

// ---- BN0: z = U_i + V_j + b0 over all (b,i,j).
// sum z   = N*(SU+SV) + M*b0
// sum z^2 = sum_b [N*SU2_b + N*SV2_b + 2*SU_b*SV_b + 2*b0*N*(SU_b+SV_b)] + M*b0^2
__global__ __launch_bounds__(256) void k_bn0(const float* __restrict__ st0,
                                             const float* __restrict__ gb0,
                                             const float* __restrict__ gg0,
                                             const float* __restrict__ gB0,
                                             float* __restrict__ c0s,
                                             float* __restrict__ c0t) {
  int c = threadIdx.x;
  float su = 0, su2 = 0, sv = 0, sv2 = 0, cross = 0;
  for (int b = 0; b < 64; ++b) {
    float a  = st0[(b * 4 + 0) * 256 + c];
    float a2 = st0[(b * 4 + 1) * 256 + c];
    float v  = st0[(b * 4 + 2) * 256 + c];
    float v2 = st0[(b * 4 + 3) * 256 + c];
    su += a; su2 += a2; sv += v; sv2 += v2; cross += a * v;
  }
  float b0 = gb0[c];
  float sumz  = 64.f * (su + sv) + kM * b0;
  float sumzz = 64.f * (su2 + sv2) + 2.f * cross + 2.f * b0 * 64.f * (su + sv) + kM * b0 * b0;
  float mu = sumz / kM;
  float var = sumzz / kM - mu * mu;
  float sc = gg0[c] * rsqrtf(var + kEps);
  c0s[c] = sc;
  c0t[c] = gB0[c] + sc * (b0 - mu);
}

// ---- U' = c0s*U + c0t ; V' = c0s*V   (f16).  a0 = relu(U'[i] + V'[j]).
__global__ __launch_bounds__(256) void k_uv(const float* __restrict__ U,
                                            const float* __restrict__ V,
                                            const float* __restrict__ c0s,
                                            const float* __restrict__ c0t,
                                            _Float16* __restrict__ Up,
                                            _Float16* __restrict__ Vp) {
  int idx = blockIdx.x * 256 + threadIdx.x;  // 262144 total, 4 elems each
  int e4 = idx * 4;
  int c4 = e4 & 255;
  float4_t u = *(const float4_t*)(U + e4);
  float4_t v = *(const float4_t*)(V + e4);
  float4_t s = *(const float4_t*)(c0s + c4);
  float4_t tt = *(const float4_t*)(c0t + c4);
  half4_t hu, hv;
#pragma unroll
  for (int e = 0; e < 4; ++e) {
    hu[e] = (_Float16)(u[e] * s[e] + tt[e]);
    hv[e] = (_Float16)(v[e] * s[e]);
  }
  *(half4_t*)(Up + e4) = hu;
  *(half4_t*)(Vp + e4) = hv;
}

// ---- GEMM1: Z1 = relu(U'+V') @ W1 + b1, plus column stats.
// grid (2048, 2). block 256 = 4 waves (2x2), output tile 128 rows x 128 cols.
// rows: b = bx>>5, i in {i0, i0+1} (i0 = (bx&31)*2), j in [0,64). row r: i = i0 + (r>>6), j = r&63.
__global__ __launch_bounds__(256) void k_gemm1(const _Float16* __restrict__ Up,
                                               const _Float16* __restrict__ Vp,
                                               const _Float16* __restrict__ W1T,
                                               const float* __restrict__ gb1,
                                               _Float16* __restrict__ Z1,
                                               float* __restrict__ stats1) {
  __shared__ __align__(16) _Float16 sU[2 * 264];
  __shared__ __align__(16) _Float16 sV[64 * 264];
  __shared__ __align__(16) _Float16 sW[128 * 72];
  const int t = threadIdx.x;
  const int bx = blockIdx.x;
  const int n0 = blockIdx.y * 128;
  const int b = bx >> 5;
  const int i0 = (bx & 31) * 2;
  const long R0 = (long)bx * 128;

  if (t < 64) {
    int row = t >> 5, k8 = (t & 31) * 8;
    *(half8*)(sU + row * 264 + k8) =
        *(const half8*)(Up + (size_t)(b * 64 + i0 + row) * 256 + k8);
  }
#pragma unroll
  for (int it = 0; it < 8; ++it) {
    int flat = it * 256 + t;
    int row = flat >> 5, k8 = (flat & 31) * 8;
    *(half8*)(sV + row * 264 + k8) =
        *(const half8*)(Vp + (size_t)(b * 64 + row) * 256 + k8);
  }

  const int wid = t >> 6, L = t & 63;
  const int wrow = wid >> 1, wcol = wid & 1;
  const int quad = L >> 4, l15 = L & 15;

  float4_t acc[4][4];
#pragma unroll
  for (int mt = 0; mt < 4; ++mt)
#pragma unroll
    for (int nt = 0; nt < 4; ++nt) acc[mt][nt] = (float4_t){0.f, 0.f, 0.f, 0.f};

  for (int kc = 0; kc < 4; ++kc) {
    __syncthreads();
#pragma unroll
    for (int it = 0; it < 4; ++it) {
      int flat = it * 256 + t;
      int n = flat >> 3, k8 = (flat & 7) * 8;
      *(half8*)(sW + n * 72 + k8) =
          *(const half8*)(W1T + (size_t)(n0 + n) * 256 + kc * 64 + k8);
    }
    __syncthreads();
#pragma unroll
    for (int ks = 0; ks < 2; ++ks) {
      const int kk = ks * 32 + quad * 8;
      const int kg = kc * 64 + kk;
      const half8 u = *(const half8*)(sU + wrow * 264 + kg);
      half8 afr[4];
#pragma unroll
      for (int mt = 0; mt < 4; ++mt) {
        half8 v = *(const half8*)(sV + (mt * 16 + l15) * 264 + kg);
        afr[mt] = relu8(u + v);
      }
      half8 bfr[4];
#pragma unroll
      for (int nt = 0; nt < 4; ++nt)
        bfr[nt] = *(const half8*)(sW + (wcol * 64 + nt * 16 + l15) * 72 + kk);
#pragma unroll
      for (int mt = 0; mt < 4; ++mt)
#pragma unroll
        for (int nt = 0; nt < 4; ++nt)
          acc[mt][nt] = __builtin_amdgcn_mfma_f32_16x16x32_f16(afr[mt], bfr[nt],
                                                               acc[mt][nt], 0, 0, 0);
    }
  }

  const int rep = bx & 31;
#pragma unroll
  for (int nt = 0; nt < 4; ++nt) {
    const int col = n0 + wcol * 64 + nt * 16 + l15;
    const float b1c = gb1[col];
    float sz = 0.f, szz = 0.f;
#pragma unroll
    for (int mt = 0; mt < 4; ++mt) {
      const size_t rowb = (size_t)(R0 + wrow * 64 + mt * 16 + quad * 4);
#pragma unroll
      for (int r = 0; r < 4; ++r) {
        float z = acc[mt][nt][r] + b1c;
        Z1[(rowb + r) * 256 + col] = (_Float16)z;
        sz += z;
        szz += z * z;
      }
    }
    sz += __shfl_xor(sz, 16, 64);
    sz += __shfl_xor(sz, 32, 64);
    szz += __shfl_xor(szz, 16, 64);
    szz += __shfl_xor(szz, 32, 64);
    if (quad == 0) {
      atomicAdd(stats1 + rep * 512 + col, sz);
      atomicAdd(stats1 + rep * 512 + 256 + col, szz);
    }
  }
}

__global__ __launch_bounds__(256) void k_bn1(const float* __restrict__ stats1,
                                             const float* __restrict__ gg1,
                                             const float* __restrict__ gB1,
                                             float* __restrict__ c1s,
                                             float* __restrict__ c1t) {
  int c = threadIdx.x;
  float S = 0.f, S2 = 0.f;
  for (int rp = 0; rp < 32; ++rp) {
    S += stats1[rp * 512 + c];
    S2 += stats1[rp * 512 + 256 + c];
  }
  float mu = S / kM;
  float var = S2 / kM - mu * mu;
  float sc = gg1[c] * rsqrtf(var + kEps);
  c1s[c] = sc;
  c1t[c] = gB1[c] - sc * mu;
}

// ---- GEMM2/3: z2 = relu(c1s*Z1 + c1t) @ W2 + b2.
// FINAL=0: column stats only.  FINAL=1: a2 = relu(c2s*z2 + c2t), reduce rows -> sbuf[b][col].
template <int FINAL>
__global__ __launch_bounds__(256) void k_gemm23(const _Float16* __restrict__ Z1,
                                                const _Float16* __restrict__ W2T,
                                                const float* __restrict__ c1s,
                                                const float* __restrict__ c1t,
                                                const float* __restrict__ gb2,
                                                const float* __restrict__ c2s,
                                                const float* __restrict__ c2t,
                                                float* __restrict__ stats2,
                                                float* __restrict__ sbuf) {
  __shared__ __align__(16) _Float16 sA[128 * 72];
  __shared__ __align__(16) _Float16 sW[128 * 72];
  __shared__ __align__(16) float sS[256];
  __shared__ __align__(16) float sT[256];
  const int t = threadIdx.x;
  const int bx = blockIdx.x;
  const long R0 = (long)bx * 128;
  sS[t] = c1s[t];
  sT[t] = c1t[t];

  const int wid = t >> 6, L = t & 63;
  const int wrow = wid >> 1, wcol = wid & 1;
  const int quad = L >> 4, l15 = L & 15;

  float4_t acc[4][4];
#pragma unroll
  for (int mt = 0; mt < 4; ++mt)
#pragma unroll
    for (int nt = 0; nt < 4; ++nt) acc[mt][nt] = (float4_t){0.f, 0.f, 0.f, 0.f};

  for (int kc = 0; kc < 4; ++kc) {
    __syncthreads();
#pragma unroll
    for (int it = 0; it < 4; ++it) {
      int flat = it * 256 + t;
      int row = flat >> 3, k8 = (flat & 7) * 8;
      int kg = kc * 64 + k8;
      half8 hv = *(const half8*)(Z1 + ((size_t)R0 + row) * 256 + kg);
      float4_t s0 = *(const float4_t*)(sS + kg);
      float4_t s1 = *(const float4_t*)(sS + kg + 4);
      float4_t t0 = *(const float4_t*)(sT + kg);
      float4_t t1 = *(const float4_t*)(sT + kg + 4);
      half8 ov;
#pragma unroll
      for (int e = 0; e < 4; ++e) {
        ov[e]     = (_Float16)fmaxf(s0[e] * (float)hv[e] + t0[e], 0.f);
        ov[4 + e] = (_Float16)fmaxf(s1[e] * (float)hv[4 + e] + t1[e], 0.f);
      }
      *(half8*)(sA + row * 72 + k8) = ov;
    }
#pragma unroll
    for (int it = 0; it < 4; ++it) {
      int flat = it * 256 + t;
      int n = flat >> 3, k8 = (flat & 7) * 8;
      *(half8*)(sW + n * 72 + k8) =
          *(const half8*)(W2T + (size_t)n * 256 + kc * 64 + k8);
    }
    __syncthreads();
#pragma unroll
    for (int ks = 0; ks < 2; ++ks) {
      const int kk = ks * 32 + quad * 8;
      half8 afr[4];
#pragma unroll
      for (int mt = 0; mt < 4; ++mt)
        afr[mt] = *(const half8*)(sA + (wrow * 64 + mt * 16 + l15) * 72 + kk);
      half8 bfr[4];
#pragma unroll
      for (int nt = 0; nt < 4; ++nt)
        bfr[nt] = *(const half8*)(sW + (wcol * 64 + nt * 16 + l15) * 72 + kk);
#pragma unroll
      for (int mt = 0; mt < 4; ++mt)
#pragma unroll
        for (int nt = 0; nt < 4; ++nt)
          acc[mt][nt] = __builtin_amdgcn_mfma_f32_16x16x32_f16(afr[mt], bfr[nt],
                                                               acc[mt][nt], 0, 0, 0);
    }
  }

  const int rep = bx & 31;
#pragma unroll
  for (int nt = 0; nt < 4; ++nt) {
    const int col = wcol * 64 + nt * 16 + l15;
    const float b2c = gb2[col];
    if (FINAL) {
      const float s2 = c2s[col], t2 = c2t[col];
      float ps = 0.f;
#pragma unroll
      for (int mt = 0; mt < 4; ++mt)
#pragma unroll
        for (int r = 0; r < 4; ++r)
          ps += fmaxf(s2 * (acc[mt][nt][r] + b2c) + t2, 0.f);
      ps += __shfl_xor(ps, 16, 64);
      ps += __shfl_xor(ps, 32, 64);
      if (quad == 0) atomicAdd(sbuf + (bx >> 5) * 128 + col, ps);
    } else {
      float sz = 0.f, szz = 0.f;
#pragma unroll
      for (int mt = 0; mt < 4; ++mt)
#pragma unroll
        for (int r = 0; r < 4; ++r) {
          float z = acc[mt][nt][r] + b2c;
          sz += z;
          szz += z * z;
        }
      sz += __shfl_xor(sz, 16, 64);
      sz += __shfl_xor(sz, 32, 64);
      szz += __shfl_xor(szz, 16, 64);
      szz += __shfl_xor(szz, 32, 64);
      if (quad == 0) {
        atomicAdd(stats2 + rep * 256 + col, sz);
        atomicAdd(stats2 + rep * 256 + 128 + col, szz);
      }
    }
  }
}

__global__ __launch_bounds__(128) void k_bn2(const float* __restrict__ stats2,
                                             const float* __restrict__ gg2,
                                             const float* __restrict__ gB2,
                                             float* __restrict__ c2s,
                                             float* __restrict__ c2t) {
  int c = threadIdx.x;  // 128
  float S = 0.f, S2 = 0.f;
  for (int rp = 0; rp < 32; ++rp) {
    S += stats2[rp * 256 + c];
    S2 += stats2[rp * 256 + 128 + c];
  }
  float mu = S / kM;
  float var = S2 / kM - mu * mu;
  float sc = gg2[c] * rsqrtf(var + kEps);
  c2s[c] = sc;
  c2t[c] = gB2[c] - sc * mu;
}

// ---- F MLP: s (64x128) -> BN-ReLU(fW0) -> BN-ReLU(fW1) -> foW + fob -> out (64x128 f32)
__global__ __launch_bounds__(512) void k_f(const float* __restrict__ sbuf,
                                           const float* __restrict__ fW0, const float* __restrict__ fb0,
                                           const float* __restrict__ fg0, const float* __restrict__ fB0,
                                           const float* __restrict__ fW1, const float* __restrict__ fb1,
                                           const float* __restrict__ fg1, const float* __restrict__ fB1,
                                           const float* __restrict__ foW, const float* __restrict__ fob,
                                           float* __restrict__ out) {
  __shared__ float sIn[64 * 128];
  __shared__ float sZ[64 * 128];
  __shared__ float sP[256];
  int t = threadIdx.x;
#pragma unroll
  for (int it = 0; it < 16; ++it) sIn[it * 512 + t] = sbuf[it * 512 + t];
  __syncthreads();
  int r = t >> 3, cg = (t & 7) * 16;

  const float* Ws[2] = {fW0, fW1};
  const float* bs[2] = {fb0, fb1};
  const float* gs[2] = {fg0, fg1};
  const float* Bs[2] = {fB0, fB1};

  for (int st = 0; st < 2; ++st) {
    const float* W = Ws[st];
    float acc[16];
#pragma unroll
    for (int j = 0; j < 16; ++j) acc[j] = bs[st][cg + j];
    for (int k = 0; k < 128; ++k) {
      float xv = sIn[r * 128 + k];
      const float4_t* wr = (const float4_t*)(W + (size_t)k * 128 + cg);
      float4_t w0 = wr[0], w1 = wr[1], w2 = wr[2], w3 = wr[3];
#pragma unroll
      for (int j = 0; j < 4; ++j) {
        acc[j]      += xv * w0[j];
        acc[4 + j]  += xv * w1[j];
        acc[8 + j]  += xv * w2[j];
        acc[12 + j] += xv * w3[j];
      }
    }
#pragma unroll
    for (int j = 0; j < 16; ++j) sZ[r * 128 + cg + j] = acc[j];
    __syncthreads();
    if (t < 128) {
      float S = 0.f, S2 = 0.f;
      for (int rr = 0; rr < 64; ++rr) {
        float z = sZ[rr * 128 + t];
        S += z;
        S2 += z * z;
      }
      float mu = S / 64.f, var = S2 / 64.f - mu * mu;
      float sc = gs[st][t] * rsqrtf(var + kEps);
      sP[t] = sc;
      sP[128 + t] = Bs[st][t] - sc * mu;
    }
    __syncthreads();
#pragma unroll
    for (int it = 0; it < 16; ++it) {
      int flat = it * 512 + t;
      int c = flat & 127;
      sIn[flat] = fmaxf(sP[c] * sZ[flat] + sP[128 + c], 0.f);
    }
    __syncthreads();
  }

  float acc[16];
#pragma unroll
  for (int j = 0; j < 16; ++j) acc[j] = fob[cg + j];
  for (int k = 0; k < 128; ++k) {
    float xv = sIn[r * 128 + k];
    const float4_t* wr = (const float4_t*)(foW + (size_t)k * 128 + cg);
    float4_t w0 = wr[0], w1 = wr[1], w2 = wr[2], w3 = wr[3];
#pragma unroll
    for (int j = 0; j < 4; ++j) {
      acc[j]      += xv * w0[j];
      acc[4 + j]  += xv * w1[j];
      acc[8 + j]  += xv * w2[j];
      acc[12 + j] += xv * w3[j];
    }
  }
#pragma unroll
  for (int j = 0; j < 16; ++j) out[r * 128 + cg + j] = acc[j];
}

extern "C" void kernel_launch(void* const* d_in, const int* in_sizes, int n_in,
                              void* d_out, int out_size, void* d_ws, size_t ws_size,
                              hipStream_t stream) {
  (void)in_sizes; (void)n_in; (void)out_size; (void)ws_size;
  const float* x   = (const float*)d_in[0];
  const float* gW0 = (const float*)d_in[1];
  const float* gb0 = (const float*)d_in[2];
  const float* gg0 = (const float*)d_in[3];
  const float* gB0 = (const float*)d_in[4];
  const float* gW1 = (const float*)d_in[5];
  const float* gb1 = (const float*)d_in[6];
  const float* gg1 = (const float*)d_in[7];
  const float* gB1 = (const float*)d_in[8];
  const float* gW2 = (const float*)d_in[9];
  const float* gb2 = (const float*)d_in[10];
  const float* gg2 = (const float*)d_in[11];
  const float* gB2 = (const float*)d_in[12];
  const float* fW0 = (const float*)d_in[13];
  const float* fb0 = (const float*)d_in[14];
  const float* fg0 = (const float*)d_in[15];
  const float* fB0 = (const float*)d_in[16];
  const float* fW1 = (const float*)d_in[17];
  const float* fb1 = (const float*)d_in[18];
  const float* fg1 = (const float*)d_in[19];
  const float* fB1 = (const float*)d_in[20];
  const float* foW = (const float*)d_in[21];
  const float* fob = (const float*)d_in[22];
  float* out = (float*)d_out;

  char* ws = (char*)d_ws;
  float*    U    = (float*)(ws + OFF_U);
  float*    V    = (float*)(ws + OFF_V);
  _Float16* Up   = (_Float16*)(ws + OFF_UP);
  _Float16* Vp   = (_Float16*)(ws + OFF_VP);
  _Float16* W1T  = (_Float16*)(ws + OFF_W1T);
  _Float16* W2T  = (_Float16*)(ws + OFF_W2T);
  _Float16* Z1   = (_Float16*)(ws + OFF_Z1);
  float*    st0  = (float*)(ws + OFF_ST0);
  float*    c0s  = (float*)(ws + OFF_C0S);
  float*    c0t  = (float*)(ws + OFF_C0T);
  float*    c1s  = (float*)(ws + OFF_C1S);
  float*    c1t  = (float*)(ws + OFF_C1T);
  float*    c2s  = (float*)(ws + OFF_C2S);
  float*    c2t  = (float*)(ws + OFF_C2T);
  float*    st1  = (float*)(ws + OFF_ST1);
  float*    st2  = (float*)(ws + OFF_ST2);
  float*    sbuf = (float*)(ws + OFF_SB);

  hipMemsetAsync(ws + OFF_ST1, 0, ZERO_BYTES, stream);

  k_wt<<<384, 256, 0, stream>>>(gW1, gW2, W1T, W2T);
  k_prep<<<dim3(128, 4), 256, 0, stream>>>(x, gW0, U, V);
  k_stats0<<<64, 256, 0, stream>>>(U, V, st0);
  k_bn0<<<1, 256, 0, stream>>>(st0, gb0, gg0, gB0, c0s, c0t);
  k_uv<<<1024, 256, 0, stream>>>(U, V, c0s, c0t, Up, Vp);
  k_gemm1<<<dim3(2048, 2), 256, 0, stream>>>(Up, Vp, W1T, gb1, Z1, st1);
  k_bn1<<<1, 256, 0, stream>>>(st1, gg1, gB1, c1s, c1t);
  k_gemm23<0><<<2048, 256, 0, stream>>>(Z1, W2T, c1s, c1t, gb2, c2s, c2t, st2, sbuf);
  k_bn2<<<1, 128, 0, stream>>>(st2, gg2, gB2, c2s, c2t);
  k_gemm23<1><<<2048, 256, 0, stream>>>(Z1, W2T, c1s, c1t, gb2, c2s, c2t, st2, sbuf);
  k_f<<<1, 512, 0, stream>>>(sbuf, fW0, fb0, fg0, fB0, fW1, fb1, fg1, fB1, foW, fob, out);
}

// Round 2
// 339.342 us; speedup vs baseline: 1.4294x; 1.4294x over previous
//
#include <hip/hip_runtime.h>

// RelationNetwork fused pipeline for MI355X (gfx950).
// B=64, N=64, D=64, T=128, HG=256, HF=128, OUT=128. M = B*N*N = 262144 pair rows.
//
// Pipeline:
//  k_wt     : transpose+convert gW1 -> W1T (f16, [n][k]), gW2 -> W2T
//  k_prep   : U = x@W0[:64], V = x@W0[64:]  (fp32, 4096x256 each)
//  k_stats0 : per-b sums of U,V,U^2,V^2  (layer-0 BN stats in closed form)
//  k_bn0    : fold BN0 -> c0s (scale), c0t (shift incl. bias/beta)
//  k_uv     : U' = c0s*U + c0t, V' = c0s*V   (f16)
//  k_gemm1  : Z1 = relu(U'+V') @ W1 + b1  (f16 MFMA, a0 generated on the fly),
//             + per-column sum/sumsq atomics (32 replicas)
//  k_bn1    : finalize BN1 params
//  k_gemm23<0>: stats pass: z2 = relu(bn1(Z1)) @ W2 + b2 -> column sum/sumsq only
//  k_bn2    : finalize BN2 params
//  k_gemm23<1>: final pass: recompute z2, a2 = relu(bn2(z2)), reduce rows -> s[b][c]
//  F stage  : 3x k_fg (8-block parallel GEMM + col-stats) + 2x k_fbn (BN fold)

typedef _Float16 half8 __attribute__((ext_vector_type(8)));
typedef _Float16 half4_t __attribute__((ext_vector_type(4)));
typedef float float4_t __attribute__((ext_vector_type(4)));

static constexpr float kEps = 1e-5f;
static constexpr float kM = 262144.f;

// ---- workspace layout (bytes) ----
static constexpr size_t OFF_U   = 0;                                  // 4096*256 f32
static constexpr size_t OFF_V   = OFF_U  + (size_t)4096*256*4;
static constexpr size_t OFF_UP  = OFF_V  + (size_t)4096*256*4;        // f16
static constexpr size_t OFF_VP  = OFF_UP + (size_t)4096*256*2;
static constexpr size_t OFF_W1T = OFF_VP + (size_t)4096*256*2;        // 256x256 f16 [n][k]
static constexpr size_t OFF_W2T = OFF_W1T + (size_t)256*256*2;        // 128x256 f16 [n][k]
static constexpr size_t OFF_Z1  = OFF_W2T + (size_t)128*256*2;        // 262144x256 f16
static constexpr size_t OFF_ST0 = OFF_Z1 + (size_t)262144*256*2;      // 64*4*256 f32
static constexpr size_t OFF_C0S = OFF_ST0 + (size_t)64*4*256*4;
static constexpr size_t OFF_C0T = OFF_C0S + 1024;
static constexpr size_t OFF_C1S = OFF_C0T + 1024;
static constexpr size_t OFF_C1T = OFF_C1S + 1024;
static constexpr size_t OFF_C2S = OFF_C1T + 1024;
static constexpr size_t OFF_C2T = OFF_C2S + 512;
// ---- zeroed region start ----
static constexpr size_t OFF_ST1 = OFF_C2T + 512;                      // 32*512 f32 (zeroed)
static constexpr size_t OFF_ST2 = OFF_ST1 + (size_t)32*512*4;         // 32*256 f32 (zeroed)
static constexpr size_t OFF_SB  = OFF_ST2 + (size_t)32*256*4;         // 64*128 f32 (zeroed)
static constexpr size_t OFF_FST0 = OFF_SB + (size_t)64*128*4;         // 256 f32 (zeroed)
static constexpr size_t OFF_FST1 = OFF_FST0 + 1024;                   // 256 f32 (zeroed)
static constexpr size_t ZERO_BYTES = (size_t)32*512*4 + (size_t)32*256*4
                                   + (size_t)64*128*4 + 2048;
// ---- end zeroed region ----
static constexpr size_t OFF_FZ0  = OFF_FST1 + 1024;                   // 64*128 f32
static constexpr size_t OFF_FZ1  = OFF_FZ0 + (size_t)64*128*4;
static constexpr size_t OFF_CF0S = OFF_FZ1 + (size_t)64*128*4;        // 128 f32 each
static constexpr size_t OFF_CF0T = OFF_CF0S + 512;
static constexpr size_t OFF_CF1S = OFF_CF0T + 512;
static constexpr size_t OFF_CF1T = OFF_CF1S + 512;

static __device__ inline half8 relu8(half8 s) {
#pragma unroll
  for (int e = 0; e < 8; ++e) s[e] = s[e] > (_Float16)0 ? s[e] : (_Float16)0;
  return s;
}

// ---- W transpose/convert: W1T[n*256+k] = gW1[k*256+n]; W2T[n*256+k] = gW2[k*128+n]
__global__ __launch_bounds__(256) void k_wt(const float* __restrict__ gW1,
                                            const float* __restrict__ gW2,
                                            _Float16* __restrict__ W1T,
                                            _Float16* __restrict__ W2T) {
  int idx = blockIdx.x * 256 + threadIdx.x;
  if (idx < 65536) {
    int n = idx >> 8, k = idx & 255;
    W1T[idx] = (_Float16)gW1[k * 256 + n];
  } else if (idx < 98304) {
    int j = idx - 65536;
    int n = j >> 8, k = j & 255;
    W2T[j] = (_Float16)gW2[k * 128 + n];
  }
}

// ---- U = x @ W0[0:64,:], V = x @ W0[64:128,:]   (fp32)
__global__ __launch_bounds__(256) void k_prep(const float* __restrict__ x,
                                              const float* __restrict__ gW0,
                                              float* __restrict__ U,
                                              float* __restrict__ V) {
  __shared__ __align__(16) float sX[32 * 64];
  int t = threadIdx.x;
  int p0 = blockIdx.x * 32;
  int by = blockIdx.y;
  int hsel = by >> 1;
  int cbase = (by & 1) * 128;
#pragma unroll
  for (int it = 0; it < 2; ++it) {
    int f4 = (it * 256 + t) * 4;
    *(float4_t*)(sX + f4) = *(const float4_t*)(x + (size_t)p0 * 64 + f4);
  }
  __syncthreads();
  int r = t >> 3, cg = (t & 7) * 16;
  const float* Wb = gW0 + (size_t)(hsel * 64) * 256 + cbase + cg;
  float acc[16];
#pragma unroll
  for (int j = 0; j < 16; ++j) acc[j] = 0.f;
  for (int k = 0; k < 64; ++k) {
    float xv = sX[r * 64 + k];
    const float4_t* wr = (const float4_t*)(Wb + (size_t)k * 256);
    float4_t w0 = wr[0], w1 = wr[1], w2 = wr[2], w3 = wr[3];
#pragma unroll
    for (int j = 0; j < 4; ++j) {
      acc[j]      += xv * w0[j];
      acc[4 + j]  += xv * w1[j];
      acc[8 + j]  += xv * w2[j];
      acc[12 + j] += xv * w3[j];
    }
  }
  float* outp = (hsel ? V : U) + (size_t)(p0 + r) * 256 + cbase + cg;
#pragma unroll
  for (int q = 0; q < 4; ++q) {
    float4_t o = {acc[q * 4], acc[q * 4 + 1], acc[q * 4 + 2], acc[q * 4 + 3]};
    *(float4_t*)(outp + q * 4) = o;
  }
}

// ---- per-b sums for layer-0 closed-form BN stats
__global__ __launch_bounds__(256) void k_stats0(const float* __restrict__ U,
                                                const float* __restrict__ V,
                                                float* __restrict__ st0) {
  int b = blockIdx.x, c = threadIdx.x;
  float su = 0, su2 = 0, sv = 0, sv2 = 0;
  for (int i = 0; i < 64; ++i) {
    float u = U[(size_t)(b * 64 + i) * 256 + c];
    float v = V[(size_t)(b * 64 + i) * 256 + c];
    su += u; su2 += u * u; sv += v; sv2 += v * v;
  }
  st0[(b * 4 + 0) * 256 + c] = su;
  st0[(b * 4 + 1) * 256 + c] = su2;
  st0[(b * 4 + 2) * 256 + c] = sv;
  st0[(b * 4 + 3) * 256 + c] = sv2;
}

// ---- BN0 closed form
__global__ __launch_bounds__(256) void k_bn0(const float* __restrict__ st0,
                                             const float* __restrict__ gb0,
                                             const float* __restrict__ gg0,
                                             const float* __restrict__ gB0,
                                             float* __restrict__ c0s,
                                             float* __restrict__ c0t) {
  int c = threadIdx.x;
  float su = 0, su2 = 0, sv = 0, sv2 = 0, cross = 0;
  for (int b = 0; b < 64; ++b) {
    float a  = st0[(b * 4 + 0) * 256 + c];
    float a2 = st0[(b * 4 + 1) * 256 + c];
    float v  = st0[(b * 4 + 2) * 256 + c];
    float v2 = st0[(b * 4 + 3) * 256 + c];
    su += a; su2 += a2; sv += v; sv2 += v2; cross += a * v;
  }
  float b0 = gb0[c];
  float sumz  = 64.f * (su + sv) + kM * b0;
  float sumzz = 64.f * (su2 + sv2) + 2.f * cross + 2.f * b0 * 64.f * (su + sv) + kM * b0 * b0;
  float mu = sumz / kM;
  float var = sumzz / kM - mu * mu;
  float sc = gg0[c] * rsqrtf(var + kEps);
  c0s[c] = sc;
  c0t[c] = gB0[c] + sc * (b0 - mu);
}

// ---- U' = c0s*U + c0t ; V' = c0s*V   (f16)
__global__ __launch_bounds__(256) void k_uv(const float* __restrict__ U,
                                            const float* __restrict__ V,
                                            const float* __restrict__ c0s,
                                            const float* __restrict__ c0t,
                                            _Float16* __restrict__ Up,
                                            _Float16* __restrict__ Vp) {
  int idx = blockIdx.x * 256 + threadIdx.x;
  int e4 = idx * 4;
  int c4 = e4 & 255;
  float4_t u = *(const float4_t*)(U + e4);
  float4_t v = *(const float4_t*)(V + e4);
  float4_t s = *(const float4_t*)(c0s + c4);
  float4_t tt = *(const float4_t*)(c0t + c4);
  half4_t hu, hv;
#pragma unroll
  for (int e = 0; e < 4; ++e) {
    hu[e] = (_Float16)(u[e] * s[e] + tt[e]);
    hv[e] = (_Float16)(v[e] * s[e]);
  }
  *(half4_t*)(Up + e4) = hu;
  *(half4_t*)(Vp + e4) = hv;
}

// ---- GEMM1: Z1 = relu(U'+V') @ W1 + b1, plus column stats.
__global__ __launch_bounds__(256) void k_gemm1(const _Float16* __restrict__ Up,
                                               const _Float16* __restrict__ Vp,
                                               const _Float16* __restrict__ W1T,
                                               const float* __restrict__ gb1,
                                               _Float16* __restrict__ Z1,
                                               float* __restrict__ stats1) {
  __shared__ __align__(16) _Float16 sU[2 * 264];
  __shared__ __align__(16) _Float16 sV[64 * 264];
  __shared__ __align__(16) _Float16 sW[128 * 72];
  const int t = threadIdx.x;
  const int bx = blockIdx.x;
  const int n0 = blockIdx.y * 128;
  const int b = bx >> 5;
  const int i0 = (bx & 31) * 2;
  const long R0 = (long)bx * 128;

  if (t < 64) {
    int row = t >> 5, k8 = (t & 31) * 8;
    *(half8*)(sU + row * 264 + k8) =
        *(const half8*)(Up + (size_t)(b * 64 + i0 + row) * 256 + k8);
  }
#pragma unroll
  for (int it = 0; it < 8; ++it) {
    int flat = it * 256 + t;
    int row = flat >> 5, k8 = (flat & 31) * 8;
    *(half8*)(sV + row * 264 + k8) =
        *(const half8*)(Vp + (size_t)(b * 64 + row) * 256 + k8);
  }

  const int wid = t >> 6, L = t & 63;
  const int wrow = wid >> 1, wcol = wid & 1;
  const int quad = L >> 4, l15 = L & 15;

  float4_t acc[4][4];
#pragma unroll
  for (int mt = 0; mt < 4; ++mt)
#pragma unroll
    for (int nt = 0; nt < 4; ++nt) acc[mt][nt] = (float4_t){0.f, 0.f, 0.f, 0.f};

  for (int kc = 0; kc < 4; ++kc) {
    __syncthreads();
#pragma unroll
    for (int it = 0; it < 4; ++it) {
      int flat = it * 256 + t;
      int n = flat >> 3, k8 = (flat & 7) * 8;
      *(half8*)(sW + n * 72 + k8) =
          *(const half8*)(W1T + (size_t)(n0 + n) * 256 + kc * 64 + k8);
    }
    __syncthreads();
#pragma unroll
    for (int ks = 0; ks < 2; ++ks) {
      const int kk = ks * 32 + quad * 8;
      const int kg = kc * 64 + kk;
      const half8 u = *(const half8*)(sU + wrow * 264 + kg);
      half8 afr[4];
#pragma unroll
      for (int mt = 0; mt < 4; ++mt) {
        half8 v = *(const half8*)(sV + (mt * 16 + l15) * 264 + kg);
        afr[mt] = relu8(u + v);
      }
      half8 bfr[4];
#pragma unroll
      for (int nt = 0; nt < 4; ++nt)
        bfr[nt] = *(const half8*)(sW + (wcol * 64 + nt * 16 + l15) * 72 + kk);
#pragma unroll
      for (int mt = 0; mt < 4; ++mt)
#pragma unroll
        for (int nt = 0; nt < 4; ++nt)
          acc[mt][nt] = __builtin_amdgcn_mfma_f32_16x16x32_f16(afr[mt], bfr[nt],
                                                               acc[mt][nt], 0, 0, 0);
    }
  }

  const int rep = bx & 31;
#pragma unroll
  for (int nt = 0; nt < 4; ++nt) {
    const int col = n0 + wcol * 64 + nt * 16 + l15;
    const float b1c = gb1[col];
    float sz = 0.f, szz = 0.f;
#pragma unroll
    for (int mt = 0; mt < 4; ++mt) {
      const size_t rowb = (size_t)(R0 + wrow * 64 + mt * 16 + quad * 4);
#pragma unroll
      for (int r = 0; r < 4; ++r) {
        float z = acc[mt][nt][r] + b1c;
        Z1[(rowb + r) * 256 + col] = (_Float16)z;
        sz += z;
        szz += z * z;
      }
    }
    sz += __shfl_xor(sz, 16, 64);
    sz += __shfl_xor(sz, 32, 64);
    szz += __shfl_xor(szz, 16, 64);
    szz += __shfl_xor(szz, 32, 64);
    if (quad == 0) {
      atomicAdd(stats1 + rep * 512 + col, sz);
      atomicAdd(stats1 + rep * 512 + 256 + col, szz);
    }
  }
}

__global__ __launch_bounds__(256) void k_bn1(const float* __restrict__ stats1,
                                             const float* __restrict__ gg1,
                                             const float* __restrict__ gB1,
                                             float* __restrict__ c1s,
                                             float* __restrict__ c1t) {
  int c = threadIdx.x;
  float S = 0.f, S2 = 0.f;
  for (int rp = 0; rp < 32; ++rp) {
    S += stats1[rp * 512 + c];
    S2 += stats1[rp * 512 + 256 + c];
  }
  float mu = S / kM;
  float var = S2 / kM - mu * mu;
  float sc = gg1[c] * rsqrtf(var + kEps);
  c1s[c] = sc;
  c1t[c] = gB1[c] - sc * mu;
}

// ---- GEMM2/3: z2 = relu(c1s*Z1 + c1t) @ W2 + b2.
template <int FINAL>
__global__ __launch_bounds__(256) void k_gemm23(const _Float16* __restrict__ Z1,
                                                const _Float16* __restrict__ W2T,
                                                const float* __restrict__ c1s,
                                                const float* __restrict__ c1t,
                                                const float* __restrict__ gb2,
                                                const float* __restrict__ c2s,
                                                const float* __restrict__ c2t,
                                                float* __restrict__ stats2,
                                                float* __restrict__ sbuf) {
  __shared__ __align__(16) _Float16 sA[128 * 72];
  __shared__ __align__(16) _Float16 sW[128 * 72];
  __shared__ __align__(16) float sS[256];
  __shared__ __align__(16) float sT[256];
  const int t = threadIdx.x;
  const int bx = blockIdx.x;
  const long R0 = (long)bx * 128;
  sS[t] = c1s[t];
  sT[t] = c1t[t];

  const int wid = t >> 6, L = t & 63;
  const int wrow = wid >> 1, wcol = wid & 1;
  const int quad = L >> 4, l15 = L & 15;

  float4_t acc[4][4];
#pragma unroll
  for (int mt = 0; mt < 4; ++mt)
#pragma unroll
    for (int nt = 0; nt < 4; ++nt) acc[mt][nt] = (float4_t){0.f, 0.f, 0.f, 0.f};

  for (int kc = 0; kc < 4; ++kc) {
    __syncthreads();
#pragma unroll
    for (int it = 0; it < 4; ++it) {
      int flat = it * 256 + t;
      int row = flat >> 3, k8 = (flat & 7) * 8;
      int kg = kc * 64 + k8;
      half8 hv = *(const half8*)(Z1 + ((size_t)R0 + row) * 256 + kg);
      float4_t s0 = *(const float4_t*)(sS + kg);
      float4_t s1 = *(const float4_t*)(sS + kg + 4);
      float4_t t0 = *(const float4_t*)(sT + kg);
      float4_t t1 = *(const float4_t*)(sT + kg + 4);
      half8 ov;
#pragma unroll
      for (int e = 0; e < 4; ++e) {
        ov[e]     = (_Float16)fmaxf(s0[e] * (float)hv[e] + t0[e], 0.f);
        ov[4 + e] = (_Float16)fmaxf(s1[e] * (float)hv[4 + e] + t1[e], 0.f);
      }
      *(half8*)(sA + row * 72 + k8) = ov;
    }
#pragma unroll
    for (int it = 0; it < 4; ++it) {
      int flat = it * 256 + t;
      int n = flat >> 3, k8 = (flat & 7) * 8;
      *(half8*)(sW + n * 72 + k8) =
          *(const half8*)(W2T + (size_t)n * 256 + kc * 64 + k8);
    }
    __syncthreads();
#pragma unroll
    for (int ks = 0; ks < 2; ++ks) {
      const int kk = ks * 32 + quad * 8;
      half8 afr[4];
#pragma unroll
      for (int mt = 0; mt < 4; ++mt)
        afr[mt] = *(const half8*)(sA + (wrow * 64 + mt * 16 + l15) * 72 + kk);
      half8 bfr[4];
#pragma unroll
      for (int nt = 0; nt < 4; ++nt)
        bfr[nt] = *(const half8*)(sW + (wcol * 64 + nt * 16 + l15) * 72 + kk);
#pragma unroll
      for (int mt = 0; mt < 4; ++mt)
#pragma unroll
        for (int nt = 0; nt < 4; ++nt)
          acc[mt][nt] = __builtin_amdgcn_mfma_f32_16x16x32_f16(afr[mt], bfr[nt],
                                                               acc[mt][nt], 0, 0, 0);
    }
  }

  const int rep = bx & 31;
#pragma unroll
  for (int nt = 0; nt < 4; ++nt) {
    const int col = wcol * 64 + nt * 16 + l15;
    const float b2c = gb2[col];
    if (FINAL) {
      const float s2 = c2s[col], t2 = c2t[col];
      float ps = 0.f;
#pragma unroll
      for (int mt = 0; mt < 4; ++mt)
#pragma unroll
        for (int r = 0; r < 4; ++r)
          ps += fmaxf(s2 * (acc[mt][nt][r] + b2c) + t2, 0.f);
      ps += __shfl_xor(ps, 16, 64);
      ps += __shfl_xor(ps, 32, 64);
      if (quad == 0) atomicAdd(sbuf + (bx >> 5) * 128 + col, ps);
    } else {
      float sz = 0.f, szz = 0.f;
#pragma unroll
      for (int mt = 0; mt < 4; ++mt)
#pragma unroll
        for (int r = 0; r < 4; ++r) {
          float z = acc[mt][nt][r] + b2c;
          sz += z;
          szz += z * z;
        }
      sz += __shfl_xor(sz, 16, 64);
      sz += __shfl_xor(sz, 32, 64);
      szz += __shfl_xor(szz, 16, 64);
      szz += __shfl_xor(szz, 32, 64);
      if (quad == 0) {
        atomicAdd(stats2 + rep * 256 + col, sz);
        atomicAdd(stats2 + rep * 256 + 128 + col, szz);
      }
    }
  }
}

__global__ __launch_bounds__(128) void k_bn2(const float* __restrict__ stats2,
                                             const float* __restrict__ gg2,
                                             const float* __restrict__ gB2,
                                             float* __restrict__ c2s,
                                             float* __restrict__ c2t) {
  int c = threadIdx.x;  // 128
  float S = 0.f, S2 = 0.f;
  for (int rp = 0; rp < 32; ++rp) {
    S += stats2[rp * 256 + c];
    S2 += stats2[rp * 256 + 128 + c];
  }
  float mu = S / kM;
  float var = S2 / kM - mu * mu;
  float sc = gg2[c] * rsqrtf(var + kEps);
  c2s[c] = sc;
  c2t[c] = gB2[c] - sc * mu;
}

// ---- F-stage GEMM: 64x128 @ 128x128 (+bias). 8 blocks x 256 threads, 8 rows/block.
// APPLY_BN: input is z-prev; apply a = relu(cs*z + ct) while staging to LDS.
// STATS: accumulate column sum/sumsq of z-out into stats (atomics, pre-zeroed).
template <bool APPLY_BN, bool STATS>
__global__ __launch_bounds__(256) void k_fg(const float* __restrict__ in,
                                            const float* __restrict__ cs,
                                            const float* __restrict__ ct,
                                            const float* __restrict__ W,
                                            const float* __restrict__ bias,
                                            float* __restrict__ zout,
                                            float* __restrict__ stats) {
  __shared__ __align__(16) float sIn[8 * 128];
  __shared__ __align__(16) float sZ[8 * 128];
  const int t = threadIdx.x;
  const int r0 = blockIdx.x * 8;
  {
    int flat = t * 4;            // 1024 floats = 8 rows x 128
    int col = flat & 127;
    float4_t v = *(const float4_t*)(in + (size_t)r0 * 128 + flat);
    if (APPLY_BN) {
      float4_t s = *(const float4_t*)(cs + col);
      float4_t sh = *(const float4_t*)(ct + col);
#pragma unroll
      for (int e = 0; e < 4; ++e) v[e] = fmaxf(s[e] * v[e] + sh[e], 0.f);
    }
    *(float4_t*)(sIn + flat) = v;
  }
  __syncthreads();

  const int r = t >> 5;          // 8 rows
  const int c4 = (t & 31) * 4;   // 128 cols / 4
  float4_t acc = *(const float4_t*)(bias + c4);
  for (int k = 0; k < 128; ++k) {
    float xv = sIn[r * 128 + k];
    float4_t w = *(const float4_t*)(W + (size_t)k * 128 + c4);
#pragma unroll
    for (int e = 0; e < 4; ++e) acc[e] += xv * w[e];
  }
  *(float4_t*)(zout + (size_t)(r0 + r) * 128 + c4) = acc;

  if (STATS) {
    *(float4_t*)(sZ + r * 128 + c4) = acc;
    __syncthreads();
    if (t < 128) {
      float S = 0.f, S2 = 0.f;
#pragma unroll
      for (int rr = 0; rr < 8; ++rr) {
        float z = sZ[rr * 128 + t];
        S += z;
        S2 += z * z;
      }
      atomicAdd(stats + t, S);
      atomicAdd(stats + 128 + t, S2);
    }
  }
}

// ---- F-stage BN fold: stats over 64 rows -> scale/shift
__global__ __launch_bounds__(128) void k_fbn(const float* __restrict__ stats,
                                             const float* __restrict__ g,
                                             const float* __restrict__ B,
                                             float* __restrict__ cs,
                                             float* __restrict__ ct) {
  int c = threadIdx.x;
  float S = stats[c], S2 = stats[128 + c];
  float mu = S / 64.f;
  float var = S2 / 64.f - mu * mu;
  float sc = g[c] * rsqrtf(var + kEps);
  cs[c] = sc;
  ct[c] = B[c] - sc * mu;
}

extern "C" void kernel_launch(void* const* d_in, const int* in_sizes, int n_in,
                              void* d_out, int out_size, void* d_ws, size_t ws_size,
                              hipStream_t stream) {
  (void)in_sizes; (void)n_in; (void)out_size; (void)ws_size;
  const float* x   = (const float*)d_in[0];
  const float* gW0 = (const float*)d_in[1];
  const float* gb0 = (const float*)d_in[2];
  const float* gg0 = (const float*)d_in[3];
  const float* gB0 = (const float*)d_in[4];
  const float* gW1 = (const float*)d_in[5];
  const float* gb1 = (const float*)d_in[6];
  const float* gg1 = (const float*)d_in[7];
  const float* gB1 = (const float*)d_in[8];
  const float* gW2 = (const float*)d_in[9];
  const float* gb2 = (const float*)d_in[10];
  const float* gg2 = (const float*)d_in[11];
  const float* gB2 = (const float*)d_in[12];
  const float* fW0 = (const float*)d_in[13];
  const float* fb0 = (const float*)d_in[14];
  const float* fg0 = (const float*)d_in[15];
  const float* fB0 = (const float*)d_in[16];
  const float* fW1 = (const float*)d_in[17];
  const float* fb1 = (const float*)d_in[18];
  const float* fg1 = (const float*)d_in[19];
  const float* fB1 = (const float*)d_in[20];
  const float* foW = (const float*)d_in[21];
  const float* fob = (const float*)d_in[22];
  float* out = (float*)d_out;

  char* ws = (char*)d_ws;
  float*    U    = (float*)(ws + OFF_U);
  float*    V    = (float*)(ws + OFF_V);
  _Float16* Up   = (_Float16*)(ws + OFF_UP);
  _Float16* Vp   = (_Float16*)(ws + OFF_VP);
  _Float16* W1T  = (_Float16*)(ws + OFF_W1T);
  _Float16* W2T  = (_Float16*)(ws + OFF_W2T);
  _Float16* Z1   = (_Float16*)(ws + OFF_Z1);
  float*    st0  = (float*)(ws + OFF_ST0);
  float*    c0s  = (float*)(ws + OFF_C0S);
  float*    c0t  = (float*)(ws + OFF_C0T);
  float*    c1s  = (float*)(ws + OFF_C1S);
  float*    c1t  = (float*)(ws + OFF_C1T);
  float*    c2s  = (float*)(ws + OFF_C2S);
  float*    c2t  = (float*)(ws + OFF_C2T);
  float*    st1  = (float*)(ws + OFF_ST1);
  float*    st2  = (float*)(ws + OFF_ST2);
  float*    sbuf = (float*)(ws + OFF_SB);
  float*    fst0 = (float*)(ws + OFF_FST0);
  float*    fst1 = (float*)(ws + OFF_FST1);
  float*    fz0  = (float*)(ws + OFF_FZ0);
  float*    fz1  = (float*)(ws + OFF_FZ1);
  float*    cf0s = (float*)(ws + OFF_CF0S);
  float*    cf0t = (float*)(ws + OFF_CF0T);
  float*    cf1s = (float*)(ws + OFF_CF1S);
  float*    cf1t = (float*)(ws + OFF_CF1T);

  hipMemsetAsync(ws + OFF_ST1, 0, ZERO_BYTES, stream);

  k_wt<<<384, 256, 0, stream>>>(gW1, gW2, W1T, W2T);
  k_prep<<<dim3(128, 4), 256, 0, stream>>>(x, gW0, U, V);
  k_stats0<<<64, 256, 0, stream>>>(U, V, st0);
  k_bn0<<<1, 256, 0, stream>>>(st0, gb0, gg0, gB0, c0s, c0t);
  k_uv<<<1024, 256, 0, stream>>>(U, V, c0s, c0t, Up, Vp);
  k_gemm1<<<dim3(2048, 2), 256, 0, stream>>>(Up, Vp, W1T, gb1, Z1, st1);
  k_bn1<<<1, 256, 0, stream>>>(st1, gg1, gB1, c1s, c1t);
  k_gemm23<0><<<2048, 256, 0, stream>>>(Z1, W2T, c1s, c1t, gb2, c2s, c2t, st2, sbuf);
  k_bn2<<<1, 128, 0, stream>>>(st2, gg2, gB2, c2s, c2t);
  k_gemm23<1><<<2048, 256, 0, stream>>>(Z1, W2T, c1s, c1t, gb2, c2s, c2t, st2, sbuf);
  // F stage: parallel GEMMs + BN folds
  k_fg<false, true><<<8, 256, 0, stream>>>(sbuf, nullptr, nullptr, fW0, fb0, fz0, fst0);
  k_fbn<<<1, 128, 0, stream>>>(fst0, fg0, fB0, cf0s, cf0t);
  k_fg<true, true><<<8, 256, 0, stream>>>(fz0, cf0s, cf0t, fW1, fb1, fz1, fst1);
  k_fbn<<<1, 128, 0, stream>>>(fst1, fg1, fB1, cf1s, cf1t);
  k_fg<true, false><<<8, 256, 0, stream>>>(fz1, cf1s, cf1t, foW, fob, out, nullptr);
}

// Round 3
// 322.110 us; speedup vs baseline: 1.5059x; 1.0535x over previous
//
#include <hip/hip_runtime.h>

// RelationNetwork fused pipeline for MI355X (gfx950).
// B=64, N=64, D=64, T=128, HG=256, HF=128, OUT=128. M = B*N*N = 262144 pair rows.
//
// Pipeline (main path):
//  k_wt     : transpose+convert gW1 -> W1T (f16, [n][k]), gW2 -> W2T
//  k_prep   : U = x@W0[:64], V = x@W0[64:]  (fp32, 4096x256 each)
//  k_stats0 : per-b sums of U,V,U^2,V^2  (layer-0 BN stats in closed form)
//  k_bn0    : fold BN0 -> c0s (scale), c0t (shift incl. bias/beta)
//  k_uv     : U' = c0s*U + c0t, V' = c0s*V   (f16)
//  k_gemm1  : Z1 = relu(U'+V') @ W1 + b1  (f16 MFMA, a0 generated on the fly),
//             + per-column sum/sumsq atomics (32 replicas)
//  k_bn1    : finalize BN1 params (f32 + f16 copies)
//  k_gemm2  : z2 = relu(bn1(Z1)) @ W2 + b2 -> store Z2 (f16) + column stats
//  k_bn2    : finalize BN2 params
//  k_red    : stream Z2, apply bn2+relu, reduce rows -> sbuf[b][c]
//  F stage  : 3x k_fg (8-block parallel GEMM + col-stats) + 2x k_fbn (BN fold)
// Fallback (small ws): k_gemm23<0>/<1> recompute path (no Z2 materialization).

typedef _Float16 half8 __attribute__((ext_vector_type(8)));
typedef _Float16 half4_t __attribute__((ext_vector_type(4)));
typedef float float4_t __attribute__((ext_vector_type(4)));

static constexpr float kEps = 1e-5f;
static constexpr float kM = 262144.f;

// ---- workspace layout (bytes) ----
static constexpr size_t OFF_U   = 0;                                  // 4096*256 f32
static constexpr size_t OFF_V   = OFF_U  + (size_t)4096*256*4;
static constexpr size_t OFF_UP  = OFF_V  + (size_t)4096*256*4;        // f16
static constexpr size_t OFF_VP  = OFF_UP + (size_t)4096*256*2;
static constexpr size_t OFF_W1T = OFF_VP + (size_t)4096*256*2;        // 256x256 f16 [n][k]
static constexpr size_t OFF_W2T = OFF_W1T + (size_t)256*256*2;        // 128x256 f16 [n][k]
static constexpr size_t OFF_Z1  = OFF_W2T + (size_t)128*256*2;        // 262144x256 f16
static constexpr size_t OFF_ST0 = OFF_Z1 + (size_t)262144*256*2;      // 64*4*256 f32
static constexpr size_t OFF_C0S = OFF_ST0 + (size_t)64*4*256*4;
static constexpr size_t OFF_C0T = OFF_C0S + 1024;
static constexpr size_t OFF_C1S = OFF_C0T + 1024;
static constexpr size_t OFF_C1T = OFF_C1S + 1024;
static constexpr size_t OFF_C2S = OFF_C1T + 1024;
static constexpr size_t OFF_C2T = OFF_C2S + 512;
// ---- zeroed region start ----
static constexpr size_t OFF_ST1 = OFF_C2T + 512;                      // 32*512 f32 (zeroed)
static constexpr size_t OFF_ST2 = OFF_ST1 + (size_t)32*512*4;         // 32*256 f32 (zeroed)
static constexpr size_t OFF_SB  = OFF_ST2 + (size_t)32*256*4;         // 64*128 f32 (zeroed)
static constexpr size_t OFF_FST0 = OFF_SB + (size_t)64*128*4;         // 256 f32 (zeroed)
static constexpr size_t OFF_FST1 = OFF_FST0 + 1024;                   // 256 f32 (zeroed)
static constexpr size_t ZERO_BYTES = (size_t)32*512*4 + (size_t)32*256*4
                                   + (size_t)64*128*4 + 2048;
// ---- end zeroed region ----
static constexpr size_t OFF_FZ0  = OFF_FST1 + 1024;                   // 64*128 f32
static constexpr size_t OFF_FZ1  = OFF_FZ0 + (size_t)64*128*4;
static constexpr size_t OFF_CF0S = OFF_FZ1 + (size_t)64*128*4;        // 128 f32 each
static constexpr size_t OFF_CF0T = OFF_CF0S + 512;
static constexpr size_t OFF_CF1S = OFF_CF0T + 512;
static constexpr size_t OFF_CF1T = OFF_CF1S + 512;
static constexpr size_t OFF_C1H  = OFF_CF1T + 512;                    // 256 f16 scale + 256 f16 shift
static constexpr size_t OFF_Z2   = OFF_C1H + 1024;                    // 262144x128 f16
static constexpr size_t WS_REQUIRED = OFF_Z2 + (size_t)262144*128*2;

static __device__ inline half8 relu8(half8 s) {
#pragma unroll
  for (int e = 0; e < 8; ++e) s[e] = s[e] > (_Float16)0 ? s[e] : (_Float16)0;
  return s;
}

// ---- W transpose/convert: W1T[n*256+k] = gW1[k*256+n]; W2T[n*256+k] = gW2[k*128+n]
__global__ __launch_bounds__(256) void k_wt(const float* __restrict__ gW1,
                                            const float* __restrict__ gW2,
                                            _Float16* __restrict__ W1T,
                                            _Float16* __restrict__ W2T) {
  int idx = blockIdx.x * 256 + threadIdx.x;
  if (idx < 65536) {
    int n = idx >> 8, k = idx & 255;
    W1T[idx] = (_Float16)gW1[k * 256 + n];
  } else if (idx < 98304) {
    int j = idx - 65536;
    int n = j >> 8, k = j & 255;
    W2T[j] = (_Float16)gW2[k * 128 + n];
  }
}

// ---- U = x @ W0[0:64,:], V = x @ W0[64:128,:]   (fp32)
__global__ __launch_bounds__(256) void k_prep(const float* __restrict__ x,
                                              const float* __restrict__ gW0,
                                              float* __restrict__ U,
                                              float* __restrict__ V) {
  __shared__ __align__(16) float sX[32 * 64];
  int t = threadIdx.x;
  int p0 = blockIdx.x * 32;
  int by = blockIdx.y;
  int hsel = by >> 1;
  int cbase = (by & 1) * 128;
#pragma unroll
  for (int it = 0; it < 2; ++it) {
    int f4 = (it * 256 + t) * 4;
    *(float4_t*)(sX + f4) = *(const float4_t*)(x + (size_t)p0 * 64 + f4);
  }
  __syncthreads();
  int r = t >> 3, cg = (t & 7) * 16;
  const float* Wb = gW0 + (size_t)(hsel * 64) * 256 + cbase + cg;
  float acc[16];
#pragma unroll
  for (int j = 0; j < 16; ++j) acc[j] = 0.f;
  for (int k = 0; k < 64; ++k) {
    float xv = sX[r * 64 + k];
    const float4_t* wr = (const float4_t*)(Wb + (size_t)k * 256);
    float4_t w0 = wr[0], w1 = wr[1], w2 = wr[2], w3 = wr[3];
#pragma unroll
    for (int j = 0; j < 4; ++j) {
      acc[j]      += xv * w0[j];
      acc[4 + j]  += xv * w1[j];
      acc[8 + j]  += xv * w2[j];
      acc[12 + j] += xv * w3[j];
    }
  }
  float* outp = (hsel ? V : U) + (size_t)(p0 + r) * 256 + cbase + cg;
#pragma unroll
  for (int q = 0; q < 4; ++q) {
    float4_t o = {acc[q * 4], acc[q * 4 + 1], acc[q * 4 + 2], acc[q * 4 + 3]};
    *(float4_t*)(outp + q * 4) = o;
  }
}

// ---- per-b sums for layer-0 closed-form BN stats
__global__ __launch_bounds__(256) void k_stats0(const float* __restrict__ U,
                                                const float* __restrict__ V,
                                                float* __restrict__ st0) {
  int b = blockIdx.x, c = threadIdx.x;
  float su = 0, su2 = 0, sv = 0, sv2 = 0;
  for (int i = 0; i < 64; ++i) {
    float u = U[(size_t)(b * 64 + i) * 256 + c];
    float v = V[(size_t)(b * 64 + i) * 256 + c];
    su += u; su2 += u * u; sv += v; sv2 += v * v;
  }
  st0[(b * 4 + 0) * 256 + c] = su;
  st0[(b * 4 + 1) * 256 + c] = su2;
  st0[(b * 4 + 2) * 256 + c] = sv;
  st0[(b * 4 + 3) * 256 + c] = sv2;
}

// ---- BN0 closed form
__global__ __launch_bounds__(256) void k_bn0(const float* __restrict__ st0,
                                             const float* __restrict__ gb0,
                                             const float* __restrict__ gg0,
                                             const float* __restrict__ gB0,
                                             float* __restrict__ c0s,
                                             float* __restrict__ c0t) {
  int c = threadIdx.x;
  float su = 0, su2 = 0, sv = 0, sv2 = 0, cross = 0;
  for (int b = 0; b < 64; ++b) {
    float a  = st0[(b * 4 + 0) * 256 + c];
    float a2 = st0[(b * 4 + 1) * 256 + c];
    float v  = st0[(b * 4 + 2) * 256 + c];
    float v2 = st0[(b * 4 + 3) * 256 + c];
    su += a; su2 += a2; sv += v; sv2 += v2; cross += a * v;
  }
  float b0 = gb0[c];
  float sumz  = 64.f * (su + sv) + kM * b0;
  float sumzz = 64.f * (su2 + sv2) + 2.f * cross + 2.f * b0 * 64.f * (su + sv) + kM * b0 * b0;
  float mu = sumz / kM;
  float var = sumzz / kM - mu * mu;
  float sc = gg0[c] * rsqrtf(var + kEps);
  c0s[c] = sc;
  c0t[c] = gB0[c] + sc * (b0 - mu);
}

// ---- U' = c0s*U + c0t ; V' = c0s*V   (f16)
__global__ __launch_bounds__(256) void k_uv(const float* __restrict__ U,
                                            const float* __restrict__ V,
                                            const float* __restrict__ c0s,
                                            const float* __restrict__ c0t,
                                            _Float16* __restrict__ Up,
                                            _Float16* __restrict__ Vp) {
  int idx = blockIdx.x * 256 + threadIdx.x;
  int e4 = idx * 4;
  int c4 = e4 & 255;
  float4_t u = *(const float4_t*)(U + e4);
  float4_t v = *(const float4_t*)(V + e4);
  float4_t s = *(const float4_t*)(c0s + c4);
  float4_t tt = *(const float4_t*)(c0t + c4);
  half4_t hu, hv;
#pragma unroll
  for (int e = 0; e < 4; ++e) {
    hu[e] = (_Float16)(u[e] * s[e] + tt[e]);
    hv[e] = (_Float16)(v[e] * s[e]);
  }
  *(half4_t*)(Up + e4) = hu;
  *(half4_t*)(Vp + e4) = hv;
}

// ---- GEMM1: Z1 = relu(U'+V') @ W1 + b1, plus column stats.
__global__ __launch_bounds__(256) void k_gemm1(const _Float16* __restrict__ Up,
                                               const _Float16* __restrict__ Vp,
                                               const _Float16* __restrict__ W1T,
                                               const float* __restrict__ gb1,
                                               _Float16* __restrict__ Z1,
                                               float* __restrict__ stats1) {
  __shared__ __align__(16) _Float16 sU[2 * 264];
  __shared__ __align__(16) _Float16 sV[64 * 264];
  __shared__ __align__(16) _Float16 sW[128 * 72];
  const int t = threadIdx.x;
  const int bx = blockIdx.x;
  const int n0 = blockIdx.y * 128;
  const int b = bx >> 5;
  const int i0 = (bx & 31) * 2;
  const long R0 = (long)bx * 128;

  if (t < 64) {
    int row = t >> 5, k8 = (t & 31) * 8;
    *(half8*)(sU + row * 264 + k8) =
        *(const half8*)(Up + (size_t)(b * 64 + i0 + row) * 256 + k8);
  }
#pragma unroll
  for (int it = 0; it < 8; ++it) {
    int flat = it * 256 + t;
    int row = flat >> 5, k8 = (flat & 31) * 8;
    *(half8*)(sV + row * 264 + k8) =
        *(const half8*)(Vp + (size_t)(b * 64 + row) * 256 + k8);
  }

  const int wid = t >> 6, L = t & 63;
  const int wrow = wid >> 1, wcol = wid & 1;
  const int quad = L >> 4, l15 = L & 15;

  float4_t acc[4][4];
#pragma unroll
  for (int mt = 0; mt < 4; ++mt)
#pragma unroll
    for (int nt = 0; nt < 4; ++nt) acc[mt][nt] = (float4_t){0.f, 0.f, 0.f, 0.f};

  for (int kc = 0; kc < 4; ++kc) {
    __syncthreads();
#pragma unroll
    for (int it = 0; it < 4; ++it) {
      int flat = it * 256 + t;
      int n = flat >> 3, k8 = (flat & 7) * 8;
      *(half8*)(sW + n * 72 + k8) =
          *(const half8*)(W1T + (size_t)(n0 + n) * 256 + kc * 64 + k8);
    }
    __syncthreads();
#pragma unroll
    for (int ks = 0; ks < 2; ++ks) {
      const int kk = ks * 32 + quad * 8;
      const int kg = kc * 64 + kk;
      const half8 u = *(const half8*)(sU + wrow * 264 + kg);
      half8 afr[4];
#pragma unroll
      for (int mt = 0; mt < 4; ++mt) {
        half8 v = *(const half8*)(sV + (mt * 16 + l15) * 264 + kg);
        afr[mt] = relu8(u + v);
      }
      half8 bfr[4];
#pragma unroll
      for (int nt = 0; nt < 4; ++nt)
        bfr[nt] = *(const half8*)(sW + (wcol * 64 + nt * 16 + l15) * 72 + kk);
#pragma unroll
      for (int mt = 0; mt < 4; ++mt)
#pragma unroll
        for (int nt = 0; nt < 4; ++nt)
          acc[mt][nt] = __builtin_amdgcn_mfma_f32_16x16x32_f16(afr[mt], bfr[nt],
                                                               acc[mt][nt], 0, 0, 0);
    }
  }

  const int rep = bx & 31;
#pragma unroll
  for (int nt = 0; nt < 4; ++nt) {
    const int col = n0 + wcol * 64 + nt * 16 + l15;
    const float b1c = gb1[col];
    float sz = 0.f, szz = 0.f;
#pragma unroll
    for (int mt = 0; mt < 4; ++mt) {
      const size_t rowb = (size_t)(R0 + wrow * 64 + mt * 16 + quad * 4);
#pragma unroll
      for (int r = 0; r < 4; ++r) {
        float z = acc[mt][nt][r] + b1c;
        Z1[(rowb + r) * 256 + col] = (_Float16)z;
        sz += z;
        szz += z * z;
      }
    }
    sz += __shfl_xor(sz, 16, 64);
    sz += __shfl_xor(sz, 32, 64);
    szz += __shfl_xor(szz, 16, 64);
    szz += __shfl_xor(szz, 32, 64);
    if (quad == 0) {
      atomicAdd(stats1 + rep * 512 + col, sz);
      atomicAdd(stats1 + rep * 512 + 256 + col, szz);
    }
  }
}

// ---- BN1 finalize (f32 + f16 copies for fast staging in gemm2)
__global__ __launch_bounds__(256) void k_bn1(const float* __restrict__ stats1,
                                             const float* __restrict__ gg1,
                                             const float* __restrict__ gB1,
                                             float* __restrict__ c1s,
                                             float* __restrict__ c1t,
                                             _Float16* __restrict__ c1h) {
  int c = threadIdx.x;
  float S = 0.f, S2 = 0.f;
  for (int rp = 0; rp < 32; ++rp) {
    S += stats1[rp * 512 + c];
    S2 += stats1[rp * 512 + 256 + c];
  }
  float mu = S / kM;
  float var = S2 / kM - mu * mu;
  float sc = gg1[c] * rsqrtf(var + kEps);
  float sh = gB1[c] - sc * mu;
  c1s[c] = sc;
  c1t[c] = sh;
  c1h[c] = (_Float16)sc;
  c1h[256 + c] = (_Float16)sh;
}

// ---- GEMM2 (main path): z2 = relu(bn1(Z1)) @ W2 + b2; store Z2 f16 + column stats.
__global__ __launch_bounds__(256) void k_gemm2(const _Float16* __restrict__ Z1,
                                               const _Float16* __restrict__ W2T,
                                               const _Float16* __restrict__ c1h,
                                               const float* __restrict__ gb2,
                                               _Float16* __restrict__ Z2,
                                               float* __restrict__ stats2) {
  __shared__ __align__(16) _Float16 sA[128 * 72];
  __shared__ __align__(16) _Float16 sW[128 * 72];
  __shared__ __align__(16) _Float16 sSh[256];
  __shared__ __align__(16) _Float16 sTh[256];
  const int t = threadIdx.x;
  const int bx = blockIdx.x;
  const long R0 = (long)bx * 128;
  sSh[t] = c1h[t];
  sTh[t] = c1h[256 + t];

  const int wid = t >> 6, L = t & 63;
  const int wrow = wid >> 1, wcol = wid & 1;
  const int quad = L >> 4, l15 = L & 15;

  float4_t acc[4][4];
#pragma unroll
  for (int mt = 0; mt < 4; ++mt)
#pragma unroll
    for (int nt = 0; nt < 4; ++nt) acc[mt][nt] = (float4_t){0.f, 0.f, 0.f, 0.f};

  for (int kc = 0; kc < 4; ++kc) {
    __syncthreads();
#pragma unroll
    for (int it = 0; it < 4; ++it) {
      int flat = it * 256 + t;
      int row = flat >> 3, k8 = (flat & 7) * 8;
      int kg = kc * 64 + k8;
      half8 hv = *(const half8*)(Z1 + ((size_t)R0 + row) * 256 + kg);
      half8 hs = *(const half8*)(sSh + kg);
      half8 ht = *(const half8*)(sTh + kg);
      half8 ov = hv * hs + ht;
      ov = relu8(ov);
      *(half8*)(sA + row * 72 + k8) = ov;
    }
#pragma unroll
    for (int it = 0; it < 4; ++it) {
      int flat = it * 256 + t;
      int n = flat >> 3, k8 = (flat & 7) * 8;
      *(half8*)(sW + n * 72 + k8) =
          *(const half8*)(W2T + (size_t)n * 256 + kc * 64 + k8);
    }
    __syncthreads();
#pragma unroll
    for (int ks = 0; ks < 2; ++ks) {
      const int kk = ks * 32 + quad * 8;
      half8 afr[4];
#pragma unroll
      for (int mt = 0; mt < 4; ++mt)
        afr[mt] = *(const half8*)(sA + (wrow * 64 + mt * 16 + l15) * 72 + kk);
      half8 bfr[4];
#pragma unroll
      for (int nt = 0; nt < 4; ++nt)
        bfr[nt] = *(const half8*)(sW + (wcol * 64 + nt * 16 + l15) * 72 + kk);
#pragma unroll
      for (int mt = 0; mt < 4; ++mt)
#pragma unroll
        for (int nt = 0; nt < 4; ++nt)
          acc[mt][nt] = __builtin_amdgcn_mfma_f32_16x16x32_f16(afr[mt], bfr[nt],
                                                               acc[mt][nt], 0, 0, 0);
    }
  }

  const int rep = bx & 31;
#pragma unroll
  for (int nt = 0; nt < 4; ++nt) {
    const int col = wcol * 64 + nt * 16 + l15;
    const float b2c = gb2[col];
    float sz = 0.f, szz = 0.f;
#pragma unroll
    for (int mt = 0; mt < 4; ++mt) {
      const size_t rowb = (size_t)(R0 + wrow * 64 + mt * 16 + quad * 4);
#pragma unroll
      for (int r = 0; r < 4; ++r) {
        float z = acc[mt][nt][r] + b2c;
        Z2[(rowb + r) * 128 + col] = (_Float16)z;
        sz += z;
        szz += z * z;
      }
    }
    sz += __shfl_xor(sz, 16, 64);
    sz += __shfl_xor(sz, 32, 64);
    szz += __shfl_xor(szz, 16, 64);
    szz += __shfl_xor(szz, 32, 64);
    if (quad == 0) {
      atomicAdd(stats2 + rep * 256 + col, sz);
      atomicAdd(stats2 + rep * 256 + 128 + col, szz);
    }
  }
}

// ---- GEMM2/3 (fallback recompute path)
template <int FINAL>
__global__ __launch_bounds__(256) void k_gemm23(const _Float16* __restrict__ Z1,
                                                const _Float16* __restrict__ W2T,
                                                const float* __restrict__ c1s,
                                                const float* __restrict__ c1t,
                                                const float* __restrict__ gb2,
                                                const float* __restrict__ c2s,
                                                const float* __restrict__ c2t,
                                                float* __restrict__ stats2,
                                                float* __restrict__ sbuf) {
  __shared__ __align__(16) _Float16 sA[128 * 72];
  __shared__ __align__(16) _Float16 sW[128 * 72];
  __shared__ __align__(16) float sS[256];
  __shared__ __align__(16) float sT[256];
  const int t = threadIdx.x;
  const int bx = blockIdx.x;
  const long R0 = (long)bx * 128;
  sS[t] = c1s[t];
  sT[t] = c1t[t];

  const int wid = t >> 6, L = t & 63;
  const int wrow = wid >> 1, wcol = wid & 1;
  const int quad = L >> 4, l15 = L & 15;

  float4_t acc[4][4];
#pragma unroll
  for (int mt = 0; mt < 4; ++mt)
#pragma unroll
    for (int nt = 0; nt < 4; ++nt) acc[mt][nt] = (float4_t){0.f, 0.f, 0.f, 0.f};

  for (int kc = 0; kc < 4; ++kc) {
    __syncthreads();
#pragma unroll
    for (int it = 0; it < 4; ++it) {
      int flat = it * 256 + t;
      int row = flat >> 3, k8 = (flat & 7) * 8;
      int kg = kc * 64 + k8;
      half8 hv = *(const half8*)(Z1 + ((size_t)R0 + row) * 256 + kg);
      float4_t s0 = *(const float4_t*)(sS + kg);
      float4_t s1 = *(const float4_t*)(sS + kg + 4);
      float4_t t0 = *(const float4_t*)(sT + kg);
      float4_t t1 = *(const float4_t*)(sT + kg + 4);
      half8 ov;
#pragma unroll
      for (int e = 0; e < 4; ++e) {
        ov[e]     = (_Float16)fmaxf(s0[e] * (float)hv[e] + t0[e], 0.f);
        ov[4 + e] = (_Float16)fmaxf(s1[e] * (float)hv[4 + e] + t1[e], 0.f);
      }
      *(half8*)(sA + row * 72 + k8) = ov;
    }
#pragma unroll
    for (int it = 0; it < 4; ++it) {
      int flat = it * 256 + t;
      int n = flat >> 3, k8 = (flat & 7) * 8;
      *(half8*)(sW + n * 72 + k8) =
          *(const half8*)(W2T + (size_t)n * 256 + kc * 64 + k8);
    }
    __syncthreads();
#pragma unroll
    for (int ks = 0; ks < 2; ++ks) {
      const int kk = ks * 32 + quad * 8;
      half8 afr[4];
#pragma unroll
      for (int mt = 0; mt < 4; ++mt)
        afr[mt] = *(const half8*)(sA + (wrow * 64 + mt * 16 + l15) * 72 + kk);
      half8 bfr[4];
#pragma unroll
      for (int nt = 0; nt < 4; ++nt)
        bfr[nt] = *(const half8*)(sW + (wcol * 64 + nt * 16 + l15) * 72 + kk);
#pragma unroll
      for (int mt = 0; mt < 4; ++mt)
#pragma unroll
        for (int nt = 0; nt < 4; ++nt)
          acc[mt][nt] = __builtin_amdgcn_mfma_f32_16x16x32_f16(afr[mt], bfr[nt],
                                                               acc[mt][nt], 0, 0, 0);
    }
  }

  const int rep = bx & 31;
#pragma unroll
  for (int nt = 0; nt < 4; ++nt) {
    const int col = wcol * 64 + nt * 16 + l15;
    const float b2c = gb2[col];
    if (FINAL) {
      const float s2 = c2s[col], t2 = c2t[col];
      float ps = 0.f;
#pragma unroll
      for (int mt = 0; mt < 4; ++mt)
#pragma unroll
        for (int r = 0; r < 4; ++r)
          ps += fmaxf(s2 * (acc[mt][nt][r] + b2c) + t2, 0.f);
      ps += __shfl_xor(ps, 16, 64);
      ps += __shfl_xor(ps, 32, 64);
      if (quad == 0) atomicAdd(sbuf + (bx >> 5) * 128 + col, ps);
    } else {
      float sz = 0.f, szz = 0.f;
#pragma unroll
      for (int mt = 0; mt < 4; ++mt)
#pragma unroll
        for (int r = 0; r < 4; ++r) {
          float z = acc[mt][nt][r] + b2c;
          sz += z;
          szz += z * z;
        }
      sz += __shfl_xor(sz, 16, 64);
      sz += __shfl_xor(sz, 32, 64);
      szz += __shfl_xor(szz, 16, 64);
      szz += __shfl_xor(szz, 32, 64);
      if (quad == 0) {
        atomicAdd(stats2 + rep * 256 + col, sz);
        atomicAdd(stats2 + rep * 256 + 128 + col, szz);
      }
    }
  }
}

__global__ __launch_bounds__(128) void k_bn2(const float* __restrict__ stats2,
                                             const float* __restrict__ gg2,
                                             const float* __restrict__ gB2,
                                             float* __restrict__ c2s,
                                             float* __restrict__ c2t) {
  int c = threadIdx.x;  // 128
  float S = 0.f, S2 = 0.f;
  for (int rp = 0; rp < 32; ++rp) {
    S += stats2[rp * 256 + c];
    S2 += stats2[rp * 256 + 128 + c];
  }
  float mu = S / kM;
  float var = S2 / kM - mu * mu;
  float sc = gg2[c] * rsqrtf(var + kEps);
  c2s[c] = sc;
  c2t[c] = gB2[c] - sc * mu;
}

// ---- k_red: stream Z2, apply bn2+relu, reduce rows per b -> sbuf[b][c] (atomics).
// grid 2048: block bx handles rows [bx*128, +128); b = bx>>5.
__global__ __launch_bounds__(256) void k_red(const _Float16* __restrict__ Z2,
                                             const float* __restrict__ c2s,
                                             const float* __restrict__ c2t,
                                             float* __restrict__ sbuf) {
  __shared__ float sR[256 * 8];
  const int t = threadIdx.x;
  const int bx = blockIdx.x;
  const int b = bx >> 5;
  const long row0 = (long)bx * 128;
  const int rr = t >> 4;
  const int c8 = (t & 15) * 8;

  float4_t s0 = *(const float4_t*)(c2s + c8);
  float4_t s1 = *(const float4_t*)(c2s + c8 + 4);
  float4_t t0 = *(const float4_t*)(c2t + c8);
  float4_t t1 = *(const float4_t*)(c2t + c8 + 4);

  float acc[8];
#pragma unroll
  for (int e = 0; e < 8; ++e) acc[e] = 0.f;
#pragma unroll
  for (int it = 0; it < 8; ++it) {
    long row = row0 + it * 16 + rr;
    half8 h = *(const half8*)(Z2 + row * 128 + c8);
#pragma unroll
    for (int e = 0; e < 4; ++e) {
      acc[e]     += fmaxf(s0[e] * (float)h[e] + t0[e], 0.f);
      acc[4 + e] += fmaxf(s1[e] * (float)h[4 + e] + t1[e], 0.f);
    }
  }
#pragma unroll
  for (int e = 0; e < 8; ++e) sR[t * 8 + e] = acc[e];
  __syncthreads();
  if (t < 128) {
    int g = t >> 3, e = t & 7;
    float S = 0.f;
#pragma unroll
    for (int rr2 = 0; rr2 < 16; ++rr2) S += sR[rr2 * 128 + t];
    (void)g; (void)e;
    atomicAdd(sbuf + b * 128 + t, S);
  }
}

// ---- F-stage GEMM: 64x128 @ 128x128 (+bias). 8 blocks x 256 threads, 8 rows/block.
template <bool APPLY_BN, bool STATS>
__global__ __launch_bounds__(256) void k_fg(const float* __restrict__ in,
                                            const float* __restrict__ cs,
                                            const float* __restrict__ ct,
                                            const float* __restrict__ W,
                                            const float* __restrict__ bias,
                                            float* __restrict__ zout,
                                            float* __restrict__ stats) {
  __shared__ __align__(16) float sIn[8 * 128];
  __shared__ __align__(16) float sZ[8 * 128];
  const int t = threadIdx.x;
  const int r0 = blockIdx.x * 8;
  {
    int flat = t * 4;
    int col = flat & 127;
    float4_t v = *(const float4_t*)(in + (size_t)r0 * 128 + flat);
    if (APPLY_BN) {
      float4_t s = *(const float4_t*)(cs + col);
      float4_t sh = *(const float4_t*)(ct + col);
#pragma unroll
      for (int e = 0; e < 4; ++e) v[e] = fmaxf(s[e] * v[e] + sh[e], 0.f);
    }
    *(float4_t*)(sIn + flat) = v;
  }
  __syncthreads();

  const int r = t >> 5;
  const int c4 = (t & 31) * 4;
  float4_t acc = *(const float4_t*)(bias + c4);
  for (int k = 0; k < 128; ++k) {
    float xv = sIn[r * 128 + k];
    float4_t w = *(const float4_t*)(W + (size_t)k * 128 + c4);
#pragma unroll
    for (int e = 0; e < 4; ++e) acc[e] += xv * w[e];
  }
  *(float4_t*)(zout + (size_t)(r0 + r) * 128 + c4) = acc;

  if (STATS) {
    *(float4_t*)(sZ + r * 128 + c4) = acc;
    __syncthreads();
    if (t < 128) {
      float S = 0.f, S2 = 0.f;
#pragma unroll
      for (int rr = 0; rr < 8; ++rr) {
        float z = sZ[rr * 128 + t];
        S += z;
        S2 += z * z;
      }
      atomicAdd(stats + t, S);
      atomicAdd(stats + 128 + t, S2);
    }
  }
}

// ---- F-stage BN fold
__global__ __launch_bounds__(128) void k_fbn(const float* __restrict__ stats,
                                             const float* __restrict__ g,
                                             const float* __restrict__ B,
                                             float* __restrict__ cs,
                                             float* __restrict__ ct) {
  int c = threadIdx.x;
  float S = stats[c], S2 = stats[128 + c];
  float mu = S / 64.f;
  float var = S2 / 64.f - mu * mu;
  float sc = g[c] * rsqrtf(var + kEps);
  cs[c] = sc;
  ct[c] = B[c] - sc * mu;
}

extern "C" void kernel_launch(void* const* d_in, const int* in_sizes, int n_in,
                              void* d_out, int out_size, void* d_ws, size_t ws_size,
                              hipStream_t stream) {
  (void)in_sizes; (void)n_in; (void)out_size;
  const float* x   = (const float*)d_in[0];
  const float* gW0 = (const float*)d_in[1];
  const float* gb0 = (const float*)d_in[2];
  const float* gg0 = (const float*)d_in[3];
  const float* gB0 = (const float*)d_in[4];
  const float* gW1 = (const float*)d_in[5];
  const float* gb1 = (const float*)d_in[6];
  const float* gg1 = (const float*)d_in[7];
  const float* gB1 = (const float*)d_in[8];
  const float* gW2 = (const float*)d_in[9];
  const float* gb2 = (const float*)d_in[10];
  const float* gg2 = (const float*)d_in[11];
  const float* gB2 = (const float*)d_in[12];
  const float* fW0 = (const float*)d_in[13];
  const float* fb0 = (const float*)d_in[14];
  const float* fg0 = (const float*)d_in[15];
  const float* fB0 = (const float*)d_in[16];
  const float* fW1 = (const float*)d_in[17];
  const float* fb1 = (const float*)d_in[18];
  const float* fg1 = (const float*)d_in[19];
  const float* fB1 = (const float*)d_in[20];
  const float* foW = (const float*)d_in[21];
  const float* fob = (const float*)d_in[22];
  float* out = (float*)d_out;

  char* ws = (char*)d_ws;
  float*    U    = (float*)(ws + OFF_U);
  float*    V    = (float*)(ws + OFF_V);
  _Float16* Up   = (_Float16*)(ws + OFF_UP);
  _Float16* Vp   = (_Float16*)(ws + OFF_VP);
  _Float16* W1T  = (_Float16*)(ws + OFF_W1T);
  _Float16* W2T  = (_Float16*)(ws + OFF_W2T);
  _Float16* Z1   = (_Float16*)(ws + OFF_Z1);
  float*    st0  = (float*)(ws + OFF_ST0);
  float*    c0s  = (float*)(ws + OFF_C0S);
  float*    c0t  = (float*)(ws + OFF_C0T);
  float*    c1s  = (float*)(ws + OFF_C1S);
  float*    c1t  = (float*)(ws + OFF_C1T);
  float*    c2s  = (float*)(ws + OFF_C2S);
  float*    c2t  = (float*)(ws + OFF_C2T);
  float*    st1  = (float*)(ws + OFF_ST1);
  float*    st2  = (float*)(ws + OFF_ST2);
  float*    sbuf = (float*)(ws + OFF_SB);
  float*    fst0 = (float*)(ws + OFF_FST0);
  float*    fst1 = (float*)(ws + OFF_FST1);
  float*    fz0  = (float*)(ws + OFF_FZ0);
  float*    fz1  = (float*)(ws + OFF_FZ1);
  float*    cf0s = (float*)(ws + OFF_CF0S);
  float*    cf0t = (float*)(ws + OFF_CF0T);
  float*    cf1s = (float*)(ws + OFF_CF1S);
  float*    cf1t = (float*)(ws + OFF_CF1T);
  _Float16* c1h  = (_Float16*)(ws + OFF_C1H);
  _Float16* Z2   = (_Float16*)(ws + OFF_Z2);

  hipMemsetAsync(ws + OFF_ST1, 0, ZERO_BYTES, stream);

  k_wt<<<384, 256, 0, stream>>>(gW1, gW2, W1T, W2T);
  k_prep<<<dim3(128, 4), 256, 0, stream>>>(x, gW0, U, V);
  k_stats0<<<64, 256, 0, stream>>>(U, V, st0);
  k_bn0<<<1, 256, 0, stream>>>(st0, gb0, gg0, gB0, c0s, c0t);
  k_uv<<<1024, 256, 0, stream>>>(U, V, c0s, c0t, Up, Vp);
  k_gemm1<<<dim3(2048, 2), 256, 0, stream>>>(Up, Vp, W1T, gb1, Z1, st1);
  k_bn1<<<1, 256, 0, stream>>>(st1, gg1, gB1, c1s, c1t, c1h);

  if (ws_size >= WS_REQUIRED) {
    // main path: materialize Z2, cheap streaming reduce
    k_gemm2<<<2048, 256, 0, stream>>>(Z1, W2T, c1h, gb2, Z2, st2);
    k_bn2<<<1, 128, 0, stream>>>(st2, gg2, gB2, c2s, c2t);
    k_red<<<2048, 256, 0, stream>>>(Z2, c2s, c2t, sbuf);
  } else {
    // fallback: recompute z2 in a second GEMM pass
    k_gemm23<0><<<2048, 256, 0, stream>>>(Z1, W2T, c1s, c1t, gb2, c2s, c2t, st2, sbuf);
    k_bn2<<<1, 128, 0, stream>>>(st2, gg2, gB2, c2s, c2t);
    k_gemm23<1><<<2048, 256, 0, stream>>>(Z1, W2T, c1s, c1t, gb2, c2s, c2t, st2, sbuf);
  }

  // F stage
  k_fg<false, true><<<8, 256, 0, stream>>>(sbuf, nullptr, nullptr, fW0, fb0, fz0, fst0);
  k_fbn<<<1, 128, 0, stream>>>(fst0, fg0, fB0, cf0s, cf0t);
  k_fg<true, true><<<8, 256, 0, stream>>>(fz0, cf0s, cf0t, fW1, fb1, fz1, fst1);
  k_fbn<<<1, 128, 0, stream>>>(fst1, fg1, fB1, cf1s, cf1t);
  k_fg<true, false><<<8, 256, 0, stream>>>(fz1, cf1s, cf1t, foW, fob, out, nullptr);
}

// Round 4
// 311.676 us; speedup vs baseline: 1.5563x; 1.0335x over previous
//
#include <hip/hip_runtime.h>

// RelationNetwork fused pipeline for MI355X (gfx950).
// B=64, N=64, D=64, T=128, HG=256, HF=128, OUT=128. M = B*N*N = 262144 pair rows.
//
// Pipeline (main path):
//  k_wt     : transpose+convert gW1 -> W1T (f16, [n][k]), gW2 -> W2T
//  k_prep   : U = x@W0[:64], V = x@W0[64:]  (fp32, 4096x256 each)
//  k_stats0 : per-b sums of U,V,U^2,V^2  (layer-0 BN stats in closed form)
//  k_bn0    : fold BN0 -> c0s (scale), c0t (shift incl. bias/beta)
//  k_uv     : U' = c0s*U + c0t, V' = c0s*V   (f16)
//  k_gemm1  : Z1 = relu(U'+V') @ W1 + b1  (f16 MFMA, a0 generated on the fly),
//             per-kc LDS slices (low LDS -> 4 blocks/CU), LDS-staged coalesced
//             epilogue, + per-column sum/sumsq atomics (32 replicas)
//  k_bn1    : finalize BN1 params (f32 + f16 copies)
//  k_gemm2  : z2 = relu(bn1(Z1)) @ W2 + b2 -> store Z2 (f16, coalesced) + column stats
//  k_bn2    : finalize BN2 params
//  k_red    : stream Z2, apply bn2+relu, reduce rows -> sbuf[b][c]
//  F stage  : 3x k_fg (8-block parallel GEMM + col-stats) + 2x k_fbn (BN fold)
// Fallback (small ws): k_gemm23<0>/<1> recompute path (no Z2 materialization).

typedef _Float16 half8 __attribute__((ext_vector_type(8)));
typedef _Float16 half4_t __attribute__((ext_vector_type(4)));
typedef float float4_t __attribute__((ext_vector_type(4)));

static constexpr float kEps = 1e-5f;
static constexpr float kM = 262144.f;

// ---- workspace layout (bytes) ----
static constexpr size_t OFF_U   = 0;                                  // 4096*256 f32
static constexpr size_t OFF_V   = OFF_U  + (size_t)4096*256*4;
static constexpr size_t OFF_UP  = OFF_V  + (size_t)4096*256*4;        // f16
static constexpr size_t OFF_VP  = OFF_UP + (size_t)4096*256*2;
static constexpr size_t OFF_W1T = OFF_VP + (size_t)4096*256*2;        // 256x256 f16 [n][k]
static constexpr size_t OFF_W2T = OFF_W1T + (size_t)256*256*2;        // 128x256 f16 [n][k]
static constexpr size_t OFF_Z1  = OFF_W2T + (size_t)128*256*2;        // 262144x256 f16
static constexpr size_t OFF_ST0 = OFF_Z1 + (size_t)262144*256*2;      // 64*4*256 f32
static constexpr size_t OFF_C0S = OFF_ST0 + (size_t)64*4*256*4;
static constexpr size_t OFF_C0T = OFF_C0S + 1024;
static constexpr size_t OFF_C1S = OFF_C0T + 1024;
static constexpr size_t OFF_C1T = OFF_C1S + 1024;
static constexpr size_t OFF_C2S = OFF_C1T + 1024;
static constexpr size_t OFF_C2T = OFF_C2S + 512;
// ---- zeroed region start ----
static constexpr size_t OFF_ST1 = OFF_C2T + 512;                      // 32*512 f32 (zeroed)
static constexpr size_t OFF_ST2 = OFF_ST1 + (size_t)32*512*4;         // 32*256 f32 (zeroed)
static constexpr size_t OFF_SB  = OFF_ST2 + (size_t)32*256*4;         // 64*128 f32 (zeroed)
static constexpr size_t OFF_FST0 = OFF_SB + (size_t)64*128*4;         // 256 f32 (zeroed)
static constexpr size_t OFF_FST1 = OFF_FST0 + 1024;                   // 256 f32 (zeroed)
static constexpr size_t ZERO_BYTES = (size_t)32*512*4 + (size_t)32*256*4
                                   + (size_t)64*128*4 + 2048;
// ---- end zeroed region ----
static constexpr size_t OFF_FZ0  = OFF_FST1 + 1024;                   // 64*128 f32
static constexpr size_t OFF_FZ1  = OFF_FZ0 + (size_t)64*128*4;
static constexpr size_t OFF_CF0S = OFF_FZ1 + (size_t)64*128*4;        // 128 f32 each
static constexpr size_t OFF_CF0T = OFF_CF0S + 512;
static constexpr size_t OFF_CF1S = OFF_CF0T + 512;
static constexpr size_t OFF_CF1T = OFF_CF1S + 512;
static constexpr size_t OFF_C1H  = OFF_CF1T + 512;                    // 256 f16 scale + 256 f16 shift
static constexpr size_t OFF_Z2   = OFF_C1H + 1024;                    // 262144x128 f16
static constexpr size_t WS_REQUIRED = OFF_Z2 + (size_t)262144*128*2;

static __device__ inline half8 relu8(half8 s) {
#pragma unroll
  for (int e = 0; e < 8; ++e) s[e] = s[e] > (_Float16)0 ? s[e] : (_Float16)0;
  return s;
}

// ---- W transpose/convert
__global__ __launch_bounds__(256) void k_wt(const float* __restrict__ gW1,
                                            const float* __restrict__ gW2,
                                            _Float16* __restrict__ W1T,
                                            _Float16* __restrict__ W2T) {
  int idx = blockIdx.x * 256 + threadIdx.x;
  if (idx < 65536) {
    int n = idx >> 8, k = idx & 255;
    W1T[idx] = (_Float16)gW1[k * 256 + n];
  } else if (idx < 98304) {
    int j = idx - 65536;
    int n = j >> 8, k = j & 255;
    W2T[j] = (_Float16)gW2[k * 128 + n];
  }
}

// ---- U = x @ W0[0:64,:], V = x @ W0[64:128,:]   (fp32)
__global__ __launch_bounds__(256) void k_prep(const float* __restrict__ x,
                                              const float* __restrict__ gW0,
                                              float* __restrict__ U,
                                              float* __restrict__ V) {
  __shared__ __align__(16) float sX[32 * 64];
  int t = threadIdx.x;
  int p0 = blockIdx.x * 32;
  int by = blockIdx.y;
  int hsel = by >> 1;
  int cbase = (by & 1) * 128;
#pragma unroll
  for (int it = 0; it < 2; ++it) {
    int f4 = (it * 256 + t) * 4;
    *(float4_t*)(sX + f4) = *(const float4_t*)(x + (size_t)p0 * 64 + f4);
  }
  __syncthreads();
  int r = t >> 3, cg = (t & 7) * 16;
  const float* Wb = gW0 + (size_t)(hsel * 64) * 256 + cbase + cg;
  float acc[16];
#pragma unroll
  for (int j = 0; j < 16; ++j) acc[j] = 0.f;
  for (int k = 0; k < 64; ++k) {
    float xv = sX[r * 64 + k];
    const float4_t* wr = (const float4_t*)(Wb + (size_t)k * 256);
    float4_t w0 = wr[0], w1 = wr[1], w2 = wr[2], w3 = wr[3];
#pragma unroll
    for (int j = 0; j < 4; ++j) {
      acc[j]      += xv * w0[j];
      acc[4 + j]  += xv * w1[j];
      acc[8 + j]  += xv * w2[j];
      acc[12 + j] += xv * w3[j];
    }
  }
  float* outp = (hsel ? V : U) + (size_t)(p0 + r) * 256 + cbase + cg;
#pragma unroll
  for (int q = 0; q < 4; ++q) {
    float4_t o = {acc[q * 4], acc[q * 4 + 1], acc[q * 4 + 2], acc[q * 4 + 3]};
    *(float4_t*)(outp + q * 4) = o;
  }
}

// ---- per-b sums for layer-0 closed-form BN stats
__global__ __launch_bounds__(256) void k_stats0(const float* __restrict__ U,
                                                const float* __restrict__ V,
                                                float* __restrict__ st0) {
  int b = blockIdx.x, c = threadIdx.x;
  float su = 0, su2 = 0, sv = 0, sv2 = 0;
  for (int i = 0; i < 64; ++i) {
    float u = U[(size_t)(b * 64 + i) * 256 + c];
    float v = V[(size_t)(b * 64 + i) * 256 + c];
    su += u; su2 += u * u; sv += v; sv2 += v * v;
  }
  st0[(b * 4 + 0) * 256 + c] = su;
  st0[(b * 4 + 1) * 256 + c] = su2;
  st0[(b * 4 + 2) * 256 + c] = sv;
  st0[(b * 4 + 3) * 256 + c] = sv2;
}

// ---- BN0 closed form
__global__ __launch_bounds__(256) void k_bn0(const float* __restrict__ st0,
                                             const float* __restrict__ gb0,
                                             const float* __restrict__ gg0,
                                             const float* __restrict__ gB0,
                                             float* __restrict__ c0s,
                                             float* __restrict__ c0t) {
  int c = threadIdx.x;
  float su = 0, su2 = 0, sv = 0, sv2 = 0, cross = 0;
  for (int b = 0; b < 64; ++b) {
    float a  = st0[(b * 4 + 0) * 256 + c];
    float a2 = st0[(b * 4 + 1) * 256 + c];
    float v  = st0[(b * 4 + 2) * 256 + c];
    float v2 = st0[(b * 4 + 3) * 256 + c];
    su += a; su2 += a2; sv += v; sv2 += v2; cross += a * v;
  }
  float b0 = gb0[c];
  float sumz  = 64.f * (su + sv) + kM * b0;
  float sumzz = 64.f * (su2 + sv2) + 2.f * cross + 2.f * b0 * 64.f * (su + sv) + kM * b0 * b0;
  float mu = sumz / kM;
  float var = sumzz / kM - mu * mu;
  float sc = gg0[c] * rsqrtf(var + kEps);
  c0s[c] = sc;
  c0t[c] = gB0[c] + sc * (b0 - mu);
}

// ---- U' = c0s*U + c0t ; V' = c0s*V   (f16)
__global__ __launch_bounds__(256) void k_uv(const float* __restrict__ U,
                                            const float* __restrict__ V,
                                            const float* __restrict__ c0s,
                                            const float* __restrict__ c0t,
                                            _Float16* __restrict__ Up,
                                            _Float16* __restrict__ Vp) {
  int idx = blockIdx.x * 256 + threadIdx.x;
  int e4 = idx * 4;
  int c4 = e4 & 255;
  float4_t u = *(const float4_t*)(U + e4);
  float4_t v = *(const float4_t*)(V + e4);
  float4_t s = *(const float4_t*)(c0s + c4);
  float4_t tt = *(const float4_t*)(c0t + c4);
  half4_t hu, hv;
#pragma unroll
  for (int e = 0; e < 4; ++e) {
    hu[e] = (_Float16)(u[e] * s[e] + tt[e]);
    hv[e] = (_Float16)(v[e] * s[e]);
  }
  *(half4_t*)(Up + e4) = hu;
  *(half4_t*)(Vp + e4) = hv;
}

// ---- GEMM1: Z1 = relu(U'+V') @ W1 + b1, plus column stats.
// grid (2048, 2). block 256 = 4 waves (2x2), output tile 128 rows x 128 cols.
// Per-kc LDS slices (pitch 72) keep loop LDS ~28 KB; epilogue reuses LDS (union,
// pitch 136) to stage the 128x128 f16 tile for coalesced 16B/lane stores.
__global__ __launch_bounds__(256) void k_gemm1(const _Float16* __restrict__ Up,
                                               const _Float16* __restrict__ Vp,
                                               const _Float16* __restrict__ W1T,
                                               const float* __restrict__ gb1,
                                               _Float16* __restrict__ Z1,
                                               float* __restrict__ stats1) {
  __shared__ __align__(16) char smem[128 * 136 * 2];  // 34816 B
  _Float16* sU = (_Float16*)smem;                       // 2 x 72
  _Float16* sV = (_Float16*)(smem + 288);               // 64 x 72
  _Float16* sW = (_Float16*)(smem + 288 + 64 * 72 * 2); // 128 x 72
  _Float16* sO = (_Float16*)smem;                       // 128 x 136 (epilogue)

  const int t = threadIdx.x;
  const int bx = blockIdx.x;
  const int n0 = blockIdx.y * 128;
  const int b = bx >> 5;
  const int i0 = (bx & 31) * 2;
  const long R0 = (long)bx * 128;

  const int wid = t >> 6, L = t & 63;
  const int wrow = wid >> 1, wcol = wid & 1;
  const int quad = L >> 4, l15 = L & 15;

  float4_t acc[4][4];
#pragma unroll
  for (int mt = 0; mt < 4; ++mt)
#pragma unroll
    for (int nt = 0; nt < 4; ++nt) acc[mt][nt] = (float4_t){0.f, 0.f, 0.f, 0.f};

  for (int kc = 0; kc < 4; ++kc) {
    __syncthreads();
    // stage sU (2x64), sV (64x64), sW (128x64) slices for this kc
    if (t < 16) {
      int row = t >> 3, c8 = (t & 7) * 8;
      *(half8*)(sU + row * 72 + c8) =
          *(const half8*)(Up + (size_t)(b * 64 + i0 + row) * 256 + kc * 64 + c8);
    }
#pragma unroll
    for (int it = 0; it < 2; ++it) {
      int flat = it * 256 + t;
      int row = flat >> 3, c8 = (flat & 7) * 8;
      *(half8*)(sV + row * 72 + c8) =
          *(const half8*)(Vp + (size_t)(b * 64 + row) * 256 + kc * 64 + c8);
    }
#pragma unroll
    for (int it = 0; it < 4; ++it) {
      int flat = it * 256 + t;
      int row = flat >> 3, c8 = (flat & 7) * 8;
      *(half8*)(sW + row * 72 + c8) =
          *(const half8*)(W1T + (size_t)(n0 + row) * 256 + kc * 64 + c8);
    }
    __syncthreads();
#pragma unroll
    for (int ks = 0; ks < 2; ++ks) {
      const int kk = ks * 32 + quad * 8;
      const half8 u = *(const half8*)(sU + wrow * 72 + kk);
      half8 afr[4];
#pragma unroll
      for (int mt = 0; mt < 4; ++mt) {
        half8 v = *(const half8*)(sV + (mt * 16 + l15) * 72 + kk);
        afr[mt] = relu8(u + v);
      }
      half8 bfr[4];
#pragma unroll
      for (int nt = 0; nt < 4; ++nt)
        bfr[nt] = *(const half8*)(sW + (wcol * 64 + nt * 16 + l15) * 72 + kk);
#pragma unroll
      for (int mt = 0; mt < 4; ++mt)
#pragma unroll
        for (int nt = 0; nt < 4; ++nt)
          acc[mt][nt] = __builtin_amdgcn_mfma_f32_16x16x32_f16(afr[mt], bfr[nt],
                                                               acc[mt][nt], 0, 0, 0);
    }
  }

  // epilogue: stats + stage tile to LDS (f16), then coalesced global store
  __syncthreads();
  const int rep = bx & 31;
#pragma unroll
  for (int nt = 0; nt < 4; ++nt) {
    const int lcol = wcol * 64 + nt * 16 + l15;
    const float b1c = gb1[n0 + lcol];
    float sz = 0.f, szz = 0.f;
#pragma unroll
    for (int mt = 0; mt < 4; ++mt) {
      const int lrow = wrow * 64 + mt * 16 + quad * 4;
#pragma unroll
      for (int r = 0; r < 4; ++r) {
        float z = acc[mt][nt][r] + b1c;
        sO[(lrow + r) * 136 + lcol] = (_Float16)z;
        sz += z;
        szz += z * z;
      }
    }
    sz += __shfl_xor(sz, 16, 64);
    sz += __shfl_xor(sz, 32, 64);
    szz += __shfl_xor(szz, 16, 64);
    szz += __shfl_xor(szz, 32, 64);
    if (quad == 0) {
      atomicAdd(stats1 + rep * 512 + n0 + lcol, sz);
      atomicAdd(stats1 + rep * 512 + 256 + n0 + lcol, szz);
    }
  }
  __syncthreads();
#pragma unroll
  for (int it = 0; it < 8; ++it) {
    int cid = it * 256 + t;
    int row = cid >> 4, ch = (cid & 15) * 8;
    half8 hv = *(const half8*)(sO + row * 136 + ch);
    *(half8*)(Z1 + (size_t)(R0 + row) * 256 + n0 + ch) = hv;
  }
}

// ---- BN1 finalize (f32 + f16 copies for fast staging in gemm2)
__global__ __launch_bounds__(256) void k_bn1(const float* __restrict__ stats1,
                                             const float* __restrict__ gg1,
                                             const float* __restrict__ gB1,
                                             float* __restrict__ c1s,
                                             float* __restrict__ c1t,
                                             _Float16* __restrict__ c1h) {
  int c = threadIdx.x;
  float S = 0.f, S2 = 0.f;
  for (int rp = 0; rp < 32; ++rp) {
    S += stats1[rp * 512 + c];
    S2 += stats1[rp * 512 + 256 + c];
  }
  float mu = S / kM;
  float var = S2 / kM - mu * mu;
  float sc = gg1[c] * rsqrtf(var + kEps);
  float sh = gB1[c] - sc * mu;
  c1s[c] = sc;
  c1t[c] = sh;
  c1h[c] = (_Float16)sc;
  c1h[256 + c] = (_Float16)sh;
}

// ---- GEMM2 (main path): z2 = relu(bn1(Z1)) @ W2 + b2; store Z2 f16 (coalesced) + stats.
__global__ __launch_bounds__(256) void k_gemm2(const _Float16* __restrict__ Z1,
                                               const _Float16* __restrict__ W2T,
                                               const _Float16* __restrict__ c1h,
                                               const float* __restrict__ gb2,
                                               _Float16* __restrict__ Z2,
                                               float* __restrict__ stats2) {
  __shared__ __align__(16) char smem[2 * 128 * 72 * 2];  // 36864 B
  _Float16* sA = (_Float16*)smem;                         // 128 x 72
  _Float16* sW = (_Float16*)(smem + 128 * 72 * 2);        // 128 x 72
  _Float16* sO = (_Float16*)smem;                         // 128 x 136 (epilogue, 34816 B)
  __shared__ __align__(16) _Float16 sSh[256];
  __shared__ __align__(16) _Float16 sTh[256];
  const int t = threadIdx.x;
  const int bx = blockIdx.x;
  const long R0 = (long)bx * 128;
  sSh[t] = c1h[t];
  sTh[t] = c1h[256 + t];

  const int wid = t >> 6, L = t & 63;
  const int wrow = wid >> 1, wcol = wid & 1;
  const int quad = L >> 4, l15 = L & 15;

  float4_t acc[4][4];
#pragma unroll
  for (int mt = 0; mt < 4; ++mt)
#pragma unroll
    for (int nt = 0; nt < 4; ++nt) acc[mt][nt] = (float4_t){0.f, 0.f, 0.f, 0.f};

  for (int kc = 0; kc < 4; ++kc) {
    __syncthreads();
#pragma unroll
    for (int it = 0; it < 2; ++it) {
      int flat = it * 256 + t;
      int row = flat >> 3, k8 = (flat & 7) * 8;
      int kg = kc * 64 + k8;
      half8 hv = *(const half8*)(Z1 + ((size_t)R0 + row) * 256 + kg);
      half8 hs = *(const half8*)(sSh + kg);
      half8 ht = *(const half8*)(sTh + kg);
      half8 ov = relu8(hv * hs + ht);
      *(half8*)(sA + row * 72 + k8) = ov;
      // second half of rows (row+64)
      int row2 = row + 64;
      half8 hv2 = *(const half8*)(Z1 + ((size_t)R0 + row2) * 256 + kg);
      half8 ov2 = relu8(hv2 * hs + ht);
      *(half8*)(sA + row2 * 72 + k8) = ov2;
    }
#pragma unroll
    for (int it = 0; it < 4; ++it) {
      int flat = it * 256 + t;
      int row = flat >> 3, k8 = (flat & 7) * 8;
      *(half8*)(sW + row * 72 + k8) =
          *(const half8*)(W2T + (size_t)row * 256 + kc * 64 + k8);
    }
    __syncthreads();
#pragma unroll
    for (int ks = 0; ks < 2; ++ks) {
      const int kk = ks * 32 + quad * 8;
      half8 afr[4];
#pragma unroll
      for (int mt = 0; mt < 4; ++mt)
        afr[mt] = *(const half8*)(sA + (wrow * 64 + mt * 16 + l15) * 72 + kk);
      half8 bfr[4];
#pragma unroll
      for (int nt = 0; nt < 4; ++nt)
        bfr[nt] = *(const half8*)(sW + (wcol * 64 + nt * 16 + l15) * 72 + kk);
#pragma unroll
      for (int mt = 0; mt < 4; ++mt)
#pragma unroll
        for (int nt = 0; nt < 4; ++nt)
          acc[mt][nt] = __builtin_amdgcn_mfma_f32_16x16x32_f16(afr[mt], bfr[nt],
                                                               acc[mt][nt], 0, 0, 0);
    }
  }

  __syncthreads();
  const int rep = bx & 31;
#pragma unroll
  for (int nt = 0; nt < 4; ++nt) {
    const int lcol = wcol * 64 + nt * 16 + l15;
    const float b2c = gb2[lcol];
    float sz = 0.f, szz = 0.f;
#pragma unroll
    for (int mt = 0; mt < 4; ++mt) {
      const int lrow = wrow * 64 + mt * 16 + quad * 4;
#pragma unroll
      for (int r = 0; r < 4; ++r) {
        float z = acc[mt][nt][r] + b2c;
        sO[(lrow + r) * 136 + lcol] = (_Float16)z;
        sz += z;
        szz += z * z;
      }
    }
    sz += __shfl_xor(sz, 16, 64);
    sz += __shfl_xor(sz, 32, 64);
    szz += __shfl_xor(szz, 16, 64);
    szz += __shfl_xor(szz, 32, 64);
    if (quad == 0) {
      atomicAdd(stats2 + rep * 256 + lcol, sz);
      atomicAdd(stats2 + rep * 256 + 128 + lcol, szz);
    }
  }
  __syncthreads();
#pragma unroll
  for (int it = 0; it < 8; ++it) {
    int cid = it * 256 + t;
    int row = cid >> 4, ch = (cid & 15) * 8;
    half8 hv = *(const half8*)(sO + row * 136 + ch);
    *(half8*)(Z2 + (size_t)(R0 + row) * 128 + ch) = hv;
  }
}

// ---- GEMM2/3 (fallback recompute path)
template <int FINAL>
__global__ __launch_bounds__(256) void k_gemm23(const _Float16* __restrict__ Z1,
                                                const _Float16* __restrict__ W2T,
                                                const float* __restrict__ c1s,
                                                const float* __restrict__ c1t,
                                                const float* __restrict__ gb2,
                                                const float* __restrict__ c2s,
                                                const float* __restrict__ c2t,
                                                float* __restrict__ stats2,
                                                float* __restrict__ sbuf) {
  __shared__ __align__(16) _Float16 sA[128 * 72];
  __shared__ __align__(16) _Float16 sW[128 * 72];
  __shared__ __align__(16) float sS[256];
  __shared__ __align__(16) float sT[256];
  const int t = threadIdx.x;
  const int bx = blockIdx.x;
  const long R0 = (long)bx * 128;
  sS[t] = c1s[t];
  sT[t] = c1t[t];

  const int wid = t >> 6, L = t & 63;
  const int wrow = wid >> 1, wcol = wid & 1;
  const int quad = L >> 4, l15 = L & 15;

  float4_t acc[4][4];
#pragma unroll
  for (int mt = 0; mt < 4; ++mt)
#pragma unroll
    for (int nt = 0; nt < 4; ++nt) acc[mt][nt] = (float4_t){0.f, 0.f, 0.f, 0.f};

  for (int kc = 0; kc < 4; ++kc) {
    __syncthreads();
#pragma unroll
    for (int it = 0; it < 4; ++it) {
      int flat = it * 256 + t;
      int row = flat >> 3, k8 = (flat & 7) * 8;
      int kg = kc * 64 + k8;
      half8 hv = *(const half8*)(Z1 + ((size_t)R0 + row) * 256 + kg);
      float4_t s0 = *(const float4_t*)(sS + kg);
      float4_t s1 = *(const float4_t*)(sS + kg + 4);
      float4_t t0 = *(const float4_t*)(sT + kg);
      float4_t t1 = *(const float4_t*)(sT + kg + 4);
      half8 ov;
#pragma unroll
      for (int e = 0; e < 4; ++e) {
        ov[e]     = (_Float16)fmaxf(s0[e] * (float)hv[e] + t0[e], 0.f);
        ov[4 + e] = (_Float16)fmaxf(s1[e] * (float)hv[4 + e] + t1[e], 0.f);
      }
      *(half8*)(sA + row * 72 + k8) = ov;
    }
#pragma unroll
    for (int it = 0; it < 4; ++it) {
      int flat = it * 256 + t;
      int n = flat >> 3, k8 = (flat & 7) * 8;
      *(half8*)(sW + n * 72 + k8) =
          *(const half8*)(W2T + (size_t)n * 256 + kc * 64 + k8);
    }
    __syncthreads();
#pragma unroll
    for (int ks = 0; ks < 2; ++ks) {
      const int kk = ks * 32 + quad * 8;
      half8 afr[4];
#pragma unroll
      for (int mt = 0; mt < 4; ++mt)
        afr[mt] = *(const half8*)(sA + (wrow * 64 + mt * 16 + l15) * 72 + kk);
      half8 bfr[4];
#pragma unroll
      for (int nt = 0; nt < 4; ++nt)
        bfr[nt] = *(const half8*)(sW + (wcol * 64 + nt * 16 + l15) * 72 + kk);
#pragma unroll
      for (int mt = 0; mt < 4; ++mt)
#pragma unroll
        for (int nt = 0; nt < 4; ++nt)
          acc[mt][nt] = __builtin_amdgcn_mfma_f32_16x16x32_f16(afr[mt], bfr[nt],
                                                               acc[mt][nt], 0, 0, 0);
    }
  }

  const int rep = bx & 31;
#pragma unroll
  for (int nt = 0; nt < 4; ++nt) {
    const int col = wcol * 64 + nt * 16 + l15;
    const float b2c = gb2[col];
    if (FINAL) {
      const float s2 = c2s[col], t2 = c2t[col];
      float ps = 0.f;
#pragma unroll
      for (int mt = 0; mt < 4; ++mt)
#pragma unroll
        for (int r = 0; r < 4; ++r)
          ps += fmaxf(s2 * (acc[mt][nt][r] + b2c) + t2, 0.f);
      ps += __shfl_xor(ps, 16, 64);
      ps += __shfl_xor(ps, 32, 64);
      if (quad == 0) atomicAdd(sbuf + (bx >> 5) * 128 + col, ps);
    } else {
      float sz = 0.f, szz = 0.f;
#pragma unroll
      for (int mt = 0; mt < 4; ++mt)
#pragma unroll
        for (int r = 0; r < 4; ++r) {
          float z = acc[mt][nt][r] + b2c;
          sz += z;
          szz += z * z;
        }
      sz += __shfl_xor(sz, 16, 64);
      sz += __shfl_xor(sz, 32, 64);
      szz += __shfl_xor(szz, 16, 64);
      szz += __shfl_xor(szz, 32, 64);
      if (quad == 0) {
        atomicAdd(stats2 + rep * 256 + col, sz);
        atomicAdd(stats2 + rep * 256 + 128 + col, szz);
      }
    }
  }
}

__global__ __launch_bounds__(128) void k_bn2(const float* __restrict__ stats2,
                                             const float* __restrict__ gg2,
                                             const float* __restrict__ gB2,
                                             float* __restrict__ c2s,
                                             float* __restrict__ c2t) {
  int c = threadIdx.x;  // 128
  float S = 0.f, S2 = 0.f;
  for (int rp = 0; rp < 32; ++rp) {
    S += stats2[rp * 256 + c];
    S2 += stats2[rp * 256 + 128 + c];
  }
  float mu = S / kM;
  float var = S2 / kM - mu * mu;
  float sc = gg2[c] * rsqrtf(var + kEps);
  c2s[c] = sc;
  c2t[c] = gB2[c] - sc * mu;
}

// ---- k_red: stream Z2, apply bn2+relu, reduce rows per b -> sbuf[b][c] (atomics).
__global__ __launch_bounds__(256) void k_red(const _Float16* __restrict__ Z2,
                                             const float* __restrict__ c2s,
                                             const float* __restrict__ c2t,
                                             float* __restrict__ sbuf) {
  __shared__ float sR[256 * 8];
  const int t = threadIdx.x;
  const int bx = blockIdx.x;
  const int b = bx >> 5;
  const long row0 = (long)bx * 128;
  const int rr = t >> 4;
  const int c8 = (t & 15) * 8;

  float4_t s0 = *(const float4_t*)(c2s + c8);
  float4_t s1 = *(const float4_t*)(c2s + c8 + 4);
  float4_t t0 = *(const float4_t*)(c2t + c8);
  float4_t t1 = *(const float4_t*)(c2t + c8 + 4);

  float acc[8];
#pragma unroll
  for (int e = 0; e < 8; ++e) acc[e] = 0.f;
#pragma unroll
  for (int it = 0; it < 8; ++it) {
    long row = row0 + it * 16 + rr;
    half8 h = *(const half8*)(Z2 + row * 128 + c8);
#pragma unroll
    for (int e = 0; e < 4; ++e) {
      acc[e]     += fmaxf(s0[e] * (float)h[e] + t0[e], 0.f);
      acc[4 + e] += fmaxf(s1[e] * (float)h[4 + e] + t1[e], 0.f);
    }
  }
#pragma unroll
  for (int e = 0; e < 8; ++e) sR[t * 8 + e] = acc[e];
  __syncthreads();
  if (t < 128) {
    float S = 0.f;
#pragma unroll
    for (int rr2 = 0; rr2 < 16; ++rr2) S += sR[rr2 * 128 + t];
    atomicAdd(sbuf + b * 128 + t, S);
  }
}

// ---- F-stage GEMM: 64x128 @ 128x128 (+bias). 8 blocks x 256 threads, 8 rows/block.
template <bool APPLY_BN, bool STATS>
__global__ __launch_bounds__(256) void k_fg(const float* __restrict__ in,
                                            const float* __restrict__ cs,
                                            const float* __restrict__ ct,
                                            const float* __restrict__ W,
                                            const float* __restrict__ bias,
                                            float* __restrict__ zout,
                                            float* __restrict__ stats) {
  __shared__ __align__(16) float sIn[8 * 128];
  __shared__ __align__(16) float sZ[8 * 128];
  const int t = threadIdx.x;
  const int r0 = blockIdx.x * 8;
  {
    int flat = t * 4;
    int col = flat & 127;
    float4_t v = *(const float4_t*)(in + (size_t)r0 * 128 + flat);
    if (APPLY_BN) {
      float4_t s = *(const float4_t*)(cs + col);
      float4_t sh = *(const float4_t*)(ct + col);
#pragma unroll
      for (int e = 0; e < 4; ++e) v[e] = fmaxf(s[e] * v[e] + sh[e], 0.f);
    }
    *(float4_t*)(sIn + flat) = v;
  }
  __syncthreads();

  const int r = t >> 5;
  const int c4 = (t & 31) * 4;
  float4_t acc = *(const float4_t*)(bias + c4);
  for (int k = 0; k < 128; ++k) {
    float xv = sIn[r * 128 + k];
    float4_t w = *(const float4_t*)(W + (size_t)k * 128 + c4);
#pragma unroll
    for (int e = 0; e < 4; ++e) acc[e] += xv * w[e];
  }
  *(float4_t*)(zout + (size_t)(r0 + r) * 128 + c4) = acc;

  if (STATS) {
    *(float4_t*)(sZ + r * 128 + c4) = acc;
    __syncthreads();
    if (t < 128) {
      float S = 0.f, S2 = 0.f;
#pragma unroll
      for (int rr = 0; rr < 8; ++rr) {
        float z = sZ[rr * 128 + t];
        S += z;
        S2 += z * z;
      }
      atomicAdd(stats + t, S);
      atomicAdd(stats + 128 + t, S2);
    }
  }
}

// ---- F-stage BN fold
__global__ __launch_bounds__(128) void k_fbn(const float* __restrict__ stats,
                                             const float* __restrict__ g,
                                             const float* __restrict__ B,
                                             float* __restrict__ cs,
                                             float* __restrict__ ct) {
  int c = threadIdx.x;
  float S = stats[c], S2 = stats[128 + c];
  float mu = S / 64.f;
  float var = S2 / 64.f - mu * mu;
  float sc = g[c] * rsqrtf(var + kEps);
  cs[c] = sc;
  ct[c] = B[c] - sc * mu;
}

extern "C" void kernel_launch(void* const* d_in, const int* in_sizes, int n_in,
                              void* d_out, int out_size, void* d_ws, size_t ws_size,
                              hipStream_t stream) {
  (void)in_sizes; (void)n_in; (void)out_size;
  const float* x   = (const float*)d_in[0];
  const float* gW0 = (const float*)d_in[1];
  const float* gb0 = (const float*)d_in[2];
  const float* gg0 = (const float*)d_in[3];
  const float* gB0 = (const float*)d_in[4];
  const float* gW1 = (const float*)d_in[5];
  const float* gb1 = (const float*)d_in[6];
  const float* gg1 = (const float*)d_in[7];
  const float* gB1 = (const float*)d_in[8];
  const float* gW2 = (const float*)d_in[9];
  const float* gb2 = (const float*)d_in[10];
  const float* gg2 = (const float*)d_in[11];
  const float* gB2 = (const float*)d_in[12];
  const float* fW0 = (const float*)d_in[13];
  const float* fb0 = (const float*)d_in[14];
  const float* fg0 = (const float*)d_in[15];
  const float* fB0 = (const float*)d_in[16];
  const float* fW1 = (const float*)d_in[17];
  const float* fb1 = (const float*)d_in[18];
  const float* fg1 = (const float*)d_in[19];
  const float* fB1 = (const float*)d_in[20];
  const float* foW = (const float*)d_in[21];
  const float* fob = (const float*)d_in[22];
  float* out = (float*)d_out;

  char* ws = (char*)d_ws;
  float*    U    = (float*)(ws + OFF_U);
  float*    V    = (float*)(ws + OFF_V);
  _Float16* Up   = (_Float16*)(ws + OFF_UP);
  _Float16* Vp   = (_Float16*)(ws + OFF_VP);
  _Float16* W1T  = (_Float16*)(ws + OFF_W1T);
  _Float16* W2T  = (_Float16*)(ws + OFF_W2T);
  _Float16* Z1   = (_Float16*)(ws + OFF_Z1);
  float*    st0  = (float*)(ws + OFF_ST0);
  float*    c0s  = (float*)(ws + OFF_C0S);
  float*    c0t  = (float*)(ws + OFF_C0T);
  float*    c1s  = (float*)(ws + OFF_C1S);
  float*    c1t  = (float*)(ws + OFF_C1T);
  float*    c2s  = (float*)(ws + OFF_C2S);
  float*    c2t  = (float*)(ws + OFF_C2T);
  float*    st1  = (float*)(ws + OFF_ST1);
  float*    st2  = (float*)(ws + OFF_ST2);
  float*    sbuf = (float*)(ws + OFF_SB);
  float*    fst0 = (float*)(ws + OFF_FST0);
  float*    fst1 = (float*)(ws + OFF_FST1);
  float*    fz0  = (float*)(ws + OFF_FZ0);
  float*    fz1  = (float*)(ws + OFF_FZ1);
  float*    cf0s = (float*)(ws + OFF_CF0S);
  float*    cf0t = (float*)(ws + OFF_CF0T);
  float*    cf1s = (float*)(ws + OFF_CF1S);
  float*    cf1t = (float*)(ws + OFF_CF1T);
  _Float16* c1h  = (_Float16*)(ws + OFF_C1H);
  _Float16* Z2   = (_Float16*)(ws + OFF_Z2);

  hipMemsetAsync(ws + OFF_ST1, 0, ZERO_BYTES, stream);

  k_wt<<<384, 256, 0, stream>>>(gW1, gW2, W1T, W2T);
  k_prep<<<dim3(128, 4), 256, 0, stream>>>(x, gW0, U, V);
  k_stats0<<<64, 256, 0, stream>>>(U, V, st0);
  k_bn0<<<1, 256, 0, stream>>>(st0, gb0, gg0, gB0, c0s, c0t);
  k_uv<<<1024, 256, 0, stream>>>(U, V, c0s, c0t, Up, Vp);
  k_gemm1<<<dim3(2048, 2), 256, 0, stream>>>(Up, Vp, W1T, gb1, Z1, st1);
  k_bn1<<<1, 256, 0, stream>>>(st1, gg1, gB1, c1s, c1t, c1h);

  if (ws_size >= WS_REQUIRED) {
    k_gemm2<<<2048, 256, 0, stream>>>(Z1, W2T, c1h, gb2, Z2, st2);
    k_bn2<<<1, 128, 0, stream>>>(st2, gg2, gB2, c2s, c2t);
    k_red<<<2048, 256, 0, stream>>>(Z2, c2s, c2t, sbuf);
  } else {
    k_gemm23<0><<<2048, 256, 0, stream>>>(Z1, W2T, c1s, c1t, gb2, c2s, c2t, st2, sbuf);
    k_bn2<<<1, 128, 0, stream>>>(st2, gg2, gB2, c2s, c2t);
    k_gemm23<1><<<2048, 256, 0, stream>>>(Z1, W2T, c1s, c1t, gb2, c2s, c2t, st2, sbuf);
  }

  // F stage
  k_fg<false, true><<<8, 256, 0, stream>>>(sbuf, nullptr, nullptr, fW0, fb0, fz0, fst0);
  k_fbn<<<1, 128, 0, stream>>>(fst0, fg0, fB0, cf0s, cf0t);
  k_fg<true, true><<<8, 256, 0, stream>>>(fz0, cf0s, cf0t, fW1, fb1, fz1, fst1);
  k_fbn<<<1, 128, 0, stream>>>(fst1, fg1, fB1, cf1s, cf1t);
  k_fg<true, false><<<8, 256, 0, stream>>>(fz1, cf1s, cf1t, foW, fob, out, nullptr);
}